// Round 1
// baseline (701.898 us; speedup 1.0000x reference)
//
#include <hip/hip_runtime.h>
#include <hip/hip_bf16.h>
#include <math.h>

// Problem dims (fixed by reference)
#define N_ROWS 8192
#define D_IN   2048
#define D_H    512
#define D_OUTF 128

typedef __attribute__((ext_vector_type(8))) short bf16x8;
typedef __attribute__((ext_vector_type(4))) float f32x4;

enum { EPI_NONE = 0, EPI_BIAS = 1, EPI_RELU = 2, EPI_SIGMOID = 3, EPI_TANHMUL = 4 };

__device__ __forceinline__ short f2bf(float f) {
    unsigned u = __builtin_bit_cast(unsigned, f);
    u += 0x7fffu + ((u >> 16) & 1u);          // RNE to bf16
    return (short)(u >> 16);
}

// ---------------------------------------------------------------------------
// bf16 MFMA GEMM: C[M,N] = epi(A[M,K] @ B[K,N] + bias), fp32 in/out, bf16 MACs.
// 128x128 tile, BK=64, 4 waves (2x2), each wave 64x64 = 4x4 frags of 16x16x32.
// A staged row-major [128][72], B staged transposed [128][72] (n-major) so each
// lane's 8 k-contiguous bf16 fragment is one ds_read_b128 (16B-aligned: 144B rows).
// ---------------------------------------------------------------------------
#define BM 128
#define BN 128
#define BK 64
#define KSTR 72   // 64 + 8 pad shorts -> 144B row stride (16B aligned, bank spread)

template<int EPI>
__global__ __launch_bounds__(256)
void gemm_bf16(const float* __restrict__ A, const float* __restrict__ B,
               const float* __restrict__ bias, const float* __restrict__ extra,
               float* __restrict__ C, int M, int N, int K)
{
    __shared__ short lds_a[BM * KSTR];
    __shared__ short lds_b[BN * KSTR];
    const int tid  = threadIdx.x;
    const int row0 = blockIdx.y * BM;
    const int col0 = blockIdx.x * BN;
    const int lane = tid & 63;
    const int wid  = tid >> 6;
    const int wr   = (wid >> 1) * 64;
    const int wc   = (wid & 1) * 64;
    const int l15  = lane & 15;
    const int lhi  = lane >> 4;

    f32x4 acc[4][4];
    #pragma unroll
    for (int i = 0; i < 4; ++i)
        #pragma unroll
        for (int j = 0; j < 4; ++j) {
            f32x4 z = {0.f, 0.f, 0.f, 0.f};
            acc[i][j] = z;
        }

    for (int kt = 0; kt < K; kt += BK) {
        // stage A tile: 128 rows x 64 k (fp32 -> bf16), 8 float4 per thread
        #pragma unroll
        for (int i = 0; i < 8; ++i) {
            int f  = tid + 256 * i;          // 0..2047 float4 slots
            int r  = f >> 4;                 // 16 float4 per row
            int c4 = (f & 15) << 2;
            float4 v = *(const float4*)(A + (size_t)(row0 + r) * K + kt + c4);
            short4 b4;
            b4.x = f2bf(v.x); b4.y = f2bf(v.y); b4.z = f2bf(v.z); b4.w = f2bf(v.w);
            *(short4*)(lds_a + r * KSTR + c4) = b4;
        }
        // stage B tile transposed: B[kt+r][col0+c] -> lds_b[c][r]
        #pragma unroll
        for (int i = 0; i < 8; ++i) {
            int f  = tid + 256 * i;          // 0..2047
            int r  = f >> 5;                 // k row 0..63 (32 float4 per row)
            int c4 = (f & 31) << 2;          // col 0..124
            float4 v = *(const float4*)(B + (size_t)(kt + r) * N + col0 + c4);
            lds_b[(c4 + 0) * KSTR + r] = f2bf(v.x);
            lds_b[(c4 + 1) * KSTR + r] = f2bf(v.y);
            lds_b[(c4 + 2) * KSTR + r] = f2bf(v.z);
            lds_b[(c4 + 3) * KSTR + r] = f2bf(v.w);
        }
        __syncthreads();
        #pragma unroll
        for (int kk = 0; kk < 2; ++kk) {
            bf16x8 af[4], bfr[4];
            #pragma unroll
            for (int mi = 0; mi < 4; ++mi)
                af[mi] = *(const bf16x8*)(lds_a + (wr + mi * 16 + l15) * KSTR + kk * 32 + lhi * 8);
            #pragma unroll
            for (int ni = 0; ni < 4; ++ni)
                bfr[ni] = *(const bf16x8*)(lds_b + (wc + ni * 16 + l15) * KSTR + kk * 32 + lhi * 8);
            #pragma unroll
            for (int mi = 0; mi < 4; ++mi)
                #pragma unroll
                for (int ni = 0; ni < 4; ++ni)
                    acc[mi][ni] = __builtin_amdgcn_mfma_f32_16x16x32_bf16(
                        af[mi], bfr[ni], acc[mi][ni], 0, 0, 0);
        }
        __syncthreads();
    }

    // epilogue: D row=(lane>>4)*4+j (A side), col=lane&15 (B side)  [m89-verified]
    #pragma unroll
    for (int mi = 0; mi < 4; ++mi) {
        #pragma unroll
        for (int ni = 0; ni < 4; ++ni) {
            const int col = col0 + wc + ni * 16 + l15;
            #pragma unroll
            for (int j = 0; j < 4; ++j) {
                const int row = row0 + wr + mi * 16 + lhi * 4 + j;
                float val = acc[mi][ni][j];
                if (EPI != EPI_NONE) val += bias[col];
                if (EPI == EPI_RELU)    val = fmaxf(val, 0.f);
                if (EPI == EPI_SIGMOID) val = 1.f / (1.f + expf(-val));
                if (EPI == EPI_TANHMUL) val = extra[(size_t)row * N + col] * tanhf(val);
                C[(size_t)row * N + col] = val;
            }
        }
    }
}

// ---------------------------------------------------------------------------
// block-wide (sum, sumsq) reduction; returns totals in all threads
// ---------------------------------------------------------------------------
template<int NT>
__device__ __forceinline__ void block_reduce2(float& s, float& s2)
{
    #pragma unroll
    for (int o = 32; o > 0; o >>= 1) {
        s  += __shfl_down(s,  o);
        s2 += __shfl_down(s2, o);
    }
    __shared__ float sm[2][NT / 64];
    const int wid  = threadIdx.x >> 6;
    const int lane = threadIdx.x & 63;
    if (lane == 0) { sm[0][wid] = s; sm[1][wid] = s2; }
    __syncthreads();
    float a = 0.f, b = 0.f;
    #pragma unroll
    for (int w = 0; w < NT / 64; ++w) { a += sm[0][w]; b += sm[1][w]; }
    s = a; s2 = b;
}

// LayerNorm over rows of F columns (in-place safe: row fully read before write)
template<int F, int NT>
__global__ __launch_bounds__(NT)
void ln_rows(const float* __restrict__ in, const float* __restrict__ g,
             const float* __restrict__ b, float* __restrict__ out)
{
    constexpr int PER = F / NT;
    const int row = blockIdx.x;
    const int tid = threadIdx.x;
    const float* x = in + (size_t)row * F;
    float v[PER];
    float s = 0.f, s2 = 0.f;
    #pragma unroll
    for (int i = 0; i < PER; ++i) {
        v[i] = x[tid + i * NT];
        s += v[i]; s2 += v[i] * v[i];
    }
    block_reduce2<NT>(s, s2);
    const float mean = s / F;
    const float var  = s2 / F - mean * mean;
    const float rs   = rsqrtf(var + 1e-5f);
    #pragma unroll
    for (int i = 0; i < PER; ++i) {
        int c = tid + i * NT;
        out[(size_t)row * F + c] = (v[i] - mean) * rs * g[c] + b[c];
    }
}

// out = LN(relu(u_i*t + v_i*zw_i + cb)) * g + b + resid   (rank-1 GCN + LN + residual)
template<int F, int NT>
__global__ __launch_bounds__(NT)
void gcn_fuse(const float* __restrict__ zw, const float* __restrict__ t,
              const float* __restrict__ u, const float* __restrict__ vv,
              const float* __restrict__ cb, const float* __restrict__ g,
              const float* __restrict__ b, const float* __restrict__ resid,
              float* __restrict__ out)
{
    constexpr int PER = F / NT;
    const int row = blockIdx.x;
    const int tid = threadIdx.x;
    const float ui = u[row], vi = vv[row];
    float y[PER];
    float s = 0.f, s2 = 0.f;
    #pragma unroll
    for (int i = 0; i < PER; ++i) {
        int c = tid + i * NT;
        float val = ui * t[c] + vi * zw[(size_t)row * F + c] + cb[c];
        val = fmaxf(val, 0.f);
        y[i] = val; s += val; s2 += val * val;
    }
    block_reduce2<NT>(s, s2);
    const float mean = s / F;
    const float var  = s2 / F - mean * mean;
    const float rs   = rsqrtf(var + 1e-5f);
    #pragma unroll
    for (int i = 0; i < PER; ++i) {
        int c = tid + i * NT;
        out[(size_t)row * F + c] =
            (y[i] - mean) * rs * g[c] + b[c] + resid[(size_t)row * F + c];
    }
}

// aw[row] = gate[row,:] . a3_w + a3_b ; s = sigmoid(aw)
__global__ __launch_bounds__(256)
void rowdot(const float* __restrict__ gate, const float* __restrict__ w,
            const float* __restrict__ b, float* __restrict__ aw_out,
            float* __restrict__ s_out)
{
    const int row = blockIdx.x;
    const int tid = threadIdx.x;
    const float* x = gate + (size_t)row * D_H;
    float s = x[tid] * w[tid] + x[tid + 256] * w[tid + 256];
    float dummy = 0.f;
    block_reduce2<256>(s, dummy);
    if (tid == 0) {
        float a = s + b[0];
        aw_out[row] = a;
        s_out[row]  = 1.f / (1.f + expf(-a));
    }
}

// S = sum(s); u_i = s_i*dinv_i; v_i = dinv_i^2*(1-s_i^2); zero t accumulators
__global__ __launch_bounds__(1024)
void prep(const float* __restrict__ s, float* __restrict__ u, float* __restrict__ v,
          float* __restrict__ t1, float* __restrict__ t2, float* __restrict__ t3)
{
    const int tid = threadIdx.x;
    float acc = 0.f;
    for (int i = tid; i < N_ROWS; i += 1024) acc += s[i];
    float dummy = 0.f;
    block_reduce2<1024>(acc, dummy);
    const float S = acc;
    for (int i = tid; i < N_ROWS; i += 1024) {
        float si   = s[i];
        float dinv = rsqrtf(1.f + si * (S - si));   // deg = 1 + s_i*(S - s_i)
        u[i] = si * dinv;
        v[i] = dinv * dinv * (1.f - si * si);
    }
    if (tid < D_H)   { t1[tid] = 0.f; t2[tid] = 0.f; }
    if (tid < D_OUTF)  t3[tid] = 0.f;
}

// t[c] += sum_r u[r]*zw[r][c]  (64 blocks x 128 rows, block = F threads)
__global__ void colsum(const float* __restrict__ zw, const float* __restrict__ u,
                       float* __restrict__ t, int F)
{
    const int c  = threadIdx.x;
    const int r0 = blockIdx.x * (N_ROWS / 64);
    float acc = 0.f;
    for (int r = 0; r < N_ROWS / 64; ++r)
        acc += u[r0 + r] * zw[(size_t)(r0 + r) * F + c];
    atomicAdd(&t[c], acc);
}

// mam[i][j] = s_i * s_j  (268 MB streaming write, float4)
__global__ __launch_bounds__(256)
void mam_kernel(const float* __restrict__ s, float* __restrict__ out)
{
    const float4* s4 = (const float4*)s;
    const size_t total  = (size_t)N_ROWS * (N_ROWS / 4);
    const size_t stride = (size_t)gridDim.x * 256;
    for (size_t g = (size_t)blockIdx.x * 256 + threadIdx.x; g < total; g += stride) {
        int row = (int)(g >> 11);          // 2048 float4 per row
        int c4  = (int)(g & 2047);
        float  si = s[row];
        float4 sv = s4[c4];
        float4 o;
        o.x = si * sv.x; o.y = si * sv.y; o.z = si * sv.z; o.w = si * sv.w;
        *(float4*)(out + ((size_t)row << 13) + ((size_t)c4 << 2)) = o;
    }
}

// ---------------------------------------------------------------------------
// Orchestration. ws usage: 3x [8192,512] f32 (48 MiB) + small vectors (~132 KB).
// Buffer lifetimes:
//   bufA: h0/h_ln -> gate -> x1 -> {zw3, res}
//   bufB: h -> x2
//   bufC: g1 -> zw1 -> zw2
// ---------------------------------------------------------------------------
extern "C" void kernel_launch(void* const* d_in, const int* in_sizes, int n_in,
                              void* d_out, int out_size, void* d_ws, size_t ws_size,
                              hipStream_t stream)
{
    const float* x     = (const float*)d_in[0];
    const float* p1_w  = (const float*)d_in[1];
    const float* p1_b  = (const float*)d_in[2];
    const float* ln0_g = (const float*)d_in[3];
    const float* ln0_b = (const float*)d_in[4];
    const float* p2_w  = (const float*)d_in[5];
    const float* p2_b  = (const float*)d_in[6];
    const float* a1_w  = (const float*)d_in[7];
    const float* a1_b  = (const float*)d_in[8];
    const float* a2_w  = (const float*)d_in[9];
    const float* a2_b  = (const float*)d_in[10];
    const float* a3_w  = (const float*)d_in[11];
    const float* a3_b  = (const float*)d_in[12];
    const float* c1_w  = (const float*)d_in[13];
    const float* c1_b  = (const float*)d_in[14];
    const float* ln1_g = (const float*)d_in[15];
    const float* ln1_b = (const float*)d_in[16];
    const float* c2_w  = (const float*)d_in[17];
    const float* c2_b  = (const float*)d_in[18];
    const float* ln2_g = (const float*)d_in[19];
    const float* ln2_b = (const float*)d_in[20];
    const float* c3_w  = (const float*)d_in[21];
    const float* c3_b  = (const float*)d_in[22];
    const float* ln3_g = (const float*)d_in[23];
    const float* ln3_b = (const float*)d_in[24];
    const float* res_w = (const float*)d_in[25];
    const float* res_b = (const float*)d_in[26];

    float* ws   = (float*)d_ws;
    float* bufA = ws;
    float* bufB = ws + (size_t)N_ROWS * D_H;
    float* bufC = ws + (size_t)2 * N_ROWS * D_H;
    float* sm0  = ws + (size_t)3 * N_ROWS * D_H;
    float* s_buf = sm0;
    float* u_buf = sm0 + N_ROWS;
    float* v_buf = sm0 + 2 * N_ROWS;
    float* t1    = sm0 + 3 * N_ROWS;
    float* t2    = t1 + D_H;
    float* t3    = t2 + D_H;
    float* zw3   = bufA;                               // x1 dead by then
    float* resb  = bufA + (size_t)N_ROWS * D_OUTF;

    float* out_x3  = (float*)d_out;
    float* out_aw  = out_x3 + (size_t)N_ROWS * D_OUTF;
    float* out_mam = out_aw + N_ROWS;

    dim3 blk(256);
    dim3 g512(D_H / BN, N_ROWS / BM);     // (4, 64)
    dim3 g128(D_OUTF / BN, N_ROWS / BM);  // (1, 64)

    // projection
    gemm_bf16<EPI_RELU><<<g512, blk, 0, stream>>>(x, p1_w, p1_b, nullptr, bufA, N_ROWS, D_H, D_IN);
    ln_rows<D_H, 256><<<N_ROWS, 256, 0, stream>>>(bufA, ln0_g, ln0_b, bufA);
    gemm_bf16<EPI_BIAS><<<g512, blk, 0, stream>>>(bufA, p2_w, p2_b, nullptr, bufB, N_ROWS, D_H, D_H);
    // attention gate
    gemm_bf16<EPI_SIGMOID><<<g512, blk, 0, stream>>>(bufB, a1_w, a1_b, nullptr, bufC, N_ROWS, D_H, D_H);
    gemm_bf16<EPI_TANHMUL><<<g512, blk, 0, stream>>>(bufB, a2_w, a2_b, bufC, bufA, N_ROWS, D_H, D_H);
    rowdot<<<N_ROWS, 256, 0, stream>>>(bufA, a3_w, a3_b, out_aw, s_buf);
    // rank-1 normalization coefficients + mam output
    prep<<<1, 1024, 0, stream>>>(s_buf, u_buf, v_buf, t1, t2, t3);
    mam_kernel<<<2048, 256, 0, stream>>>(s_buf, out_mam);
    // GCN layer 1
    gemm_bf16<EPI_NONE><<<g512, blk, 0, stream>>>(bufB, c1_w, nullptr, nullptr, bufC, N_ROWS, D_H, D_H);
    colsum<<<64, D_H, 0, stream>>>(bufC, u_buf, t1, D_H);
    gcn_fuse<D_H, 256><<<N_ROWS, 256, 0, stream>>>(bufC, t1, u_buf, v_buf, c1_b, ln1_g, ln1_b, bufB, bufA);
    // GCN layer 2
    gemm_bf16<EPI_NONE><<<g512, blk, 0, stream>>>(bufA, c2_w, nullptr, nullptr, bufC, N_ROWS, D_H, D_H);
    colsum<<<64, D_H, 0, stream>>>(bufC, u_buf, t2, D_H);
    gcn_fuse<D_H, 256><<<N_ROWS, 256, 0, stream>>>(bufC, t2, u_buf, v_buf, c2_b, ln2_g, ln2_b, bufA, bufB);
    // GCN layer 3 + residual projection
    gemm_bf16<EPI_NONE><<<g128, blk, 0, stream>>>(bufB, c3_w, nullptr, nullptr, zw3, N_ROWS, D_OUTF, D_H);
    colsum<<<64, D_OUTF, 0, stream>>>(zw3, u_buf, t3, D_OUTF);
    gemm_bf16<EPI_BIAS><<<g128, blk, 0, stream>>>(bufB, res_w, res_b, nullptr, resb, N_ROWS, D_OUTF, D_H);
    gcn_fuse<D_OUTF, 128><<<N_ROWS, 128, 0, stream>>>(zw3, t3, u_buf, v_buf, c3_b, ln3_g, ln3_b, resb, out_x3);
}

// Round 2
// 260.233 us; speedup vs baseline: 2.6972x; 2.6972x over previous
//
#include <hip/hip_runtime.h>
#include <hip/hip_bf16.h>
#include <math.h>

// Problem dims (fixed by reference)
#define N_ROWS 8192
#define D_IN   2048
#define D_H    512
#define D_OUTF 128

typedef __attribute__((ext_vector_type(8))) short bf16x8;
typedef __attribute__((ext_vector_type(4))) float f32x4;

enum { EPI_RELU = 0, EPI_BIAS2 = 1, EPI_SIGMOID = 2, EPI_TANHMUL = 3,
       EPI_NONE = 4, EPI_C3RES = 5 };

__device__ __forceinline__ short f2bf(float f) {
    unsigned u = __builtin_bit_cast(unsigned, f);
    u += 0x7fffu + ((u >> 16) & 1u);          // RNE to bf16
    return (short)(u >> 16);
}

// Weight scratch layout (element offsets into the mam-region scratch, shorts)
constexpr size_t OFF_P1T  = 0;          // [512][2048]
constexpr size_t OFF_P2T  = 1048576;    // [512][512]
constexpr size_t OFF_A1T  = 1310720;
constexpr size_t OFF_A2T  = 1572864;
constexpr size_t OFF_C1T  = 1835008;
constexpr size_t OFF_C2T  = 2097152;
constexpr size_t OFF_C3T  = 2359296;    // [128][512] (rows 0-127 of fused [256][512])
constexpr size_t OFF_REST = 2424832;    // [128][512] (rows 128-255)
constexpr size_t OFF_SLOT1 = 4194304;   // bf16 [8192][512] activation slot (byte 8MB)
constexpr size_t OFF_SLOT2 = 8388608;   // bf16 [8192][512] activation slot (byte 16MB)

// ---------------------------------------------------------------------------
// Batched weight transpose+convert: W[K][N] f32 -> Wt[N][K] bf16, 32x32 tiles.
// ---------------------------------------------------------------------------
__global__ __launch_bounds__(256)
void wtrans(const float* __restrict__ p1, const float* __restrict__ p2,
            const float* __restrict__ a1, const float* __restrict__ a2,
            const float* __restrict__ c1, const float* __restrict__ c2,
            const float* __restrict__ c3, const float* __restrict__ rs,
            short* __restrict__ z)
{
    __shared__ float t[32][33];
    const int w = blockIdx.y;
    const float* src; short* dst; int Kw, Nw;
    switch (w) {
        case 0: src = p1; dst = z + OFF_P1T;  Kw = 2048; Nw = 512; break;
        case 1: src = p2; dst = z + OFF_P2T;  Kw = 512;  Nw = 512; break;
        case 2: src = a1; dst = z + OFF_A1T;  Kw = 512;  Nw = 512; break;
        case 3: src = a2; dst = z + OFF_A2T;  Kw = 512;  Nw = 512; break;
        case 4: src = c1; dst = z + OFF_C1T;  Kw = 512;  Nw = 512; break;
        case 5: src = c2; dst = z + OFF_C2T;  Kw = 512;  Nw = 512; break;
        case 6: src = c3; dst = z + OFF_C3T;  Kw = 512;  Nw = 128; break;
        default: src = rs; dst = z + OFF_REST; Kw = 512; Nw = 128; break;
    }
    const int txc = Nw >> 5, tyc = Kw >> 5;
    const int tile = blockIdx.x;
    if (tile >= txc * tyc) return;
    const int tc = tile % txc, tr = tile / txc;
    const int x = threadIdx.x, y = threadIdx.y;
    #pragma unroll
    for (int j = 0; j < 4; ++j)
        t[y + 8 * j][x] = src[(size_t)(tr * 32 + y + 8 * j) * Nw + tc * 32 + x];
    __syncthreads();
    #pragma unroll
    for (int j = 0; j < 4; ++j)
        dst[(size_t)(tc * 32 + y + 8 * j) * Kw + tr * 32 + x] = f2bf(t[x][y + 8 * j]);
}

// ---------------------------------------------------------------------------
// bf16 MFMA GEMM: BM=64, BN=128, BK=64, 256 thr = 4 waves (2x2), wave tile
// 32x64 (2x4 frags of 16x16x32). A: [M][K] f32 or bf16 k-major; B: [N][K]
// bf16 k-major (pre-transposed weights). LDS XOR-swizzled (c16 ^= row&7) on
// BOTH ds_write and ds_read -> conflict-free b128 frag reads. Software
// pipeline: next tile's global loads issued before the compute barrier.
// ---------------------------------------------------------------------------
template<bool AF32, int EPI, int KT>
__global__ __launch_bounds__(256)
void gemm(const void* __restrict__ Ap, const short* __restrict__ Bt,
          const float* __restrict__ bias, const float* __restrict__ extra,
          const float* __restrict__ auxw, float* __restrict__ auxo,
          float* __restrict__ C, short* __restrict__ Cb, int N)
{
    __shared__ short lds_a[64 * 64];    // 8 KB
    __shared__ short lds_b[128 * 64];   // 16 KB
    const int tid = threadIdx.x;
    // XCD-aware swizzle (nwg % 8 == 0 for all our grids)
    const int gx   = gridDim.x;
    const int orig = blockIdx.y * gx + blockIdx.x;
    const int cpx  = (gx * gridDim.y) >> 3;
    const int wg   = (orig & 7) * cpx + (orig >> 3);
    const int bx   = wg % gx;
    const int by   = wg / gx;
    const int row0 = by * 64;
    const int col0 = bx * 128;
    const int lane = tid & 63;
    const int wid  = tid >> 6;
    const int wm   = (wid >> 1) * 32;
    const int wn   = (wid & 1) * 64;
    const int l15  = lane & 15;
    const int lhi  = lane >> 4;

    f32x4 acc[2][4];
    #pragma unroll
    for (int i = 0; i < 2; ++i)
        #pragma unroll
        for (int j = 0; j < 4; ++j) {
            f32x4 z = {0.f, 0.f, 0.f, 0.f};
            acc[i][j] = z;
        }

    auto load_a = [&](bf16x8& d0, bf16x8& d1, int kt) {
        #pragma unroll
        for (int i = 0; i < 2; ++i) {
            bf16x8& d = i ? d1 : d0;
            const int q = tid + (i << 8);      // 0..511
            const int r = q >> 3, c16 = q & 7;
            if constexpr (AF32) {
                const float* p = (const float*)Ap + (size_t)(row0 + r) * KT + kt + c16 * 8;
                float4 u0 = *(const float4*)p;
                float4 u1 = *(const float4*)(p + 4);
                bf16x8 v;
                v[0] = f2bf(u0.x); v[1] = f2bf(u0.y); v[2] = f2bf(u0.z); v[3] = f2bf(u0.w);
                v[4] = f2bf(u1.x); v[5] = f2bf(u1.y); v[6] = f2bf(u1.z); v[7] = f2bf(u1.w);
                d = v;
            } else {
                d = *(const bf16x8*)((const short*)Ap + (size_t)(row0 + r) * KT + kt + c16 * 8);
            }
        }
    };
    auto load_b = [&](bf16x8& d0, bf16x8& d1, bf16x8& d2, bf16x8& d3, int kt) {
        #pragma unroll
        for (int i = 0; i < 4; ++i) {
            bf16x8& d = (i == 0) ? d0 : (i == 1) ? d1 : (i == 2) ? d2 : d3;
            const int q = tid + (i << 8);      // 0..1023
            const int r = q >> 3, c16 = q & 7;
            d = *(const bf16x8*)(Bt + (size_t)(col0 + r) * KT + kt + c16 * 8);
        }
    };
    auto write_a = [&](bf16x8 d0, bf16x8 d1) {
        #pragma unroll
        for (int i = 0; i < 2; ++i) {
            bf16x8 d = i ? d1 : d0;
            const int q = tid + (i << 8);
            const int r = q >> 3, c16 = q & 7;
            *(bf16x8*)(lds_a + r * 64 + ((c16 ^ (r & 7)) << 3)) = d;
        }
    };
    auto write_b = [&](bf16x8 d0, bf16x8 d1, bf16x8 d2, bf16x8 d3) {
        #pragma unroll
        for (int i = 0; i < 4; ++i) {
            bf16x8 d = (i == 0) ? d0 : (i == 1) ? d1 : (i == 2) ? d2 : d3;
            const int q = tid + (i << 8);
            const int r = q >> 3, c16 = q & 7;
            *(bf16x8*)(lds_b + r * 64 + ((c16 ^ (r & 7)) << 3)) = d;
        }
    };

    constexpr int NSTEP = KT / 64;
    bf16x8 ca0, ca1, cb0, cb1, cb2, cb3;
    bf16x8 na0 = {}, na1 = {}, nb0 = {}, nb1 = {}, nb2 = {}, nb3 = {};
    load_a(ca0, ca1, 0);
    load_b(cb0, cb1, cb2, cb3, 0);

    #pragma unroll 2
    for (int s = 0; s < NSTEP; ++s) {
        __syncthreads();                   // prior compute done reading LDS
        write_a(ca0, ca1);
        write_b(cb0, cb1, cb2, cb3);
        if (s + 1 < NSTEP) {               // issue next tile early (latency hides
            load_a(na0, na1, (s + 1) * 64);//  under barrier + MFMA below)
            load_b(nb0, nb1, nb2, nb3, (s + 1) * 64);
        }
        __syncthreads();                   // tiles ready
        #pragma unroll
        for (int kk = 0; kk < 2; ++kk) {
            bf16x8 af[2], bfr[4];
            #pragma unroll
            for (int mi = 0; mi < 2; ++mi) {
                const int row = wm + mi * 16 + l15;
                af[mi] = *(const bf16x8*)(lds_a + row * 64 + (((kk * 4 + lhi) ^ (row & 7)) << 3));
            }
            #pragma unroll
            for (int ni = 0; ni < 4; ++ni) {
                const int row = wn + ni * 16 + l15;
                bfr[ni] = *(const bf16x8*)(lds_b + row * 64 + (((kk * 4 + lhi) ^ (row & 7)) << 3));
            }
            #pragma unroll
            for (int mi = 0; mi < 2; ++mi)
                #pragma unroll
                for (int ni = 0; ni < 4; ++ni)
                    acc[mi][ni] = __builtin_amdgcn_mfma_f32_16x16x32_bf16(
                        af[mi], bfr[ni], acc[mi][ni], 0, 0, 0);
        }
        ca0 = na0; ca1 = na1; cb0 = nb0; cb1 = nb1; cb2 = nb2; cb3 = nb3;
    }

    // epilogue: C/D row=(lane>>4)*4+j, col=lane&15 [m89-verified, round-1-passed]
    if constexpr (EPI == EPI_TANHMUL) {
        // gate = extra * tanh(acc + bias); partial row-dot with auxw (a3_w);
        // shfl-reduce across the 16-lane col group; atomicAdd into auxo (aw).
        float pd[2][4];
        #pragma unroll
        for (int mi = 0; mi < 2; ++mi)
            #pragma unroll
            for (int j = 0; j < 4; ++j) pd[mi][j] = 0.f;
        #pragma unroll
        for (int mi = 0; mi < 2; ++mi)
            #pragma unroll
            for (int ni = 0; ni < 4; ++ni) {
                const int col = col0 + wn + ni * 16 + l15;
                #pragma unroll
                for (int j = 0; j < 4; ++j) {
                    const int row = row0 + wm + mi * 16 + lhi * 4 + j;
                    float val = acc[mi][ni][j] + bias[col];
                    val = extra[(size_t)row * N + col] * tanhf(val);
                    pd[mi][j] += val * auxw[col];
                }
            }
        #pragma unroll
        for (int mi = 0; mi < 2; ++mi)
            #pragma unroll
            for (int j = 0; j < 4; ++j) {
                float v = pd[mi][j];
                v += __shfl_xor(v, 1); v += __shfl_xor(v, 2);
                v += __shfl_xor(v, 4); v += __shfl_xor(v, 8);
                if (l15 == 0)
                    atomicAdd(&auxo[row0 + wm + mi * 16 + lhi * 4 + j], v);
            }
    } else {
        #pragma unroll
        for (int mi = 0; mi < 2; ++mi)
            #pragma unroll
            for (int ni = 0; ni < 4; ++ni) {
                const int col = col0 + wn + ni * 16 + l15;
                #pragma unroll
                for (int j = 0; j < 4; ++j) {
                    const int row = row0 + wm + mi * 16 + lhi * 4 + j;
                    float val = acc[mi][ni][j];
                    if constexpr (EPI == EPI_RELU) {
                        val = fmaxf(val + bias[col], 0.f);
                        C[(size_t)row * N + col] = val;
                    } else if constexpr (EPI == EPI_BIAS2) {
                        val += bias[col];
                        C[(size_t)row * N + col] = val;
                        Cb[(size_t)row * N + col] = f2bf(val);
                    } else if constexpr (EPI == EPI_SIGMOID) {
                        val = 1.f / (1.f + expf(-(val + bias[col])));
                        C[(size_t)row * N + col] = val;
                    } else if constexpr (EPI == EPI_NONE) {
                        C[(size_t)row * N + col] = val;
                    } else { // EPI_C3RES: cols 0-127 -> zw3 (no bias), 128-255 -> resb (+res_b)
                        if (col < D_OUTF) C[(size_t)row * D_OUTF + col] = val;
                        else auxo[(size_t)row * D_OUTF + (col - D_OUTF)] = val + bias[col - D_OUTF];
                    }
                }
            }
        if constexpr (EPI == EPI_SIGMOID) {  // init aw = a3_b for a2's atomics
            if (bx == 0 && tid < 64) auxo[row0 + tid] = auxw[0];
        }
    }
}

// ---------------------------------------------------------------------------
// block-wide (sum, sumsq) reduction; returns totals in all threads
// ---------------------------------------------------------------------------
template<int NT>
__device__ __forceinline__ void block_reduce2(float& s, float& s2)
{
    #pragma unroll
    for (int o = 32; o > 0; o >>= 1) {
        s  += __shfl_down(s,  o);
        s2 += __shfl_down(s2, o);
    }
    __shared__ float sm[2][NT / 64];
    const int wid  = threadIdx.x >> 6;
    const int lane = threadIdx.x & 63;
    if (lane == 0) { sm[0][wid] = s; sm[1][wid] = s2; }
    __syncthreads();
    float a = 0.f, b = 0.f;
    #pragma unroll
    for (int w = 0; w < NT / 64; ++w) { a += sm[0][w]; b += sm[1][w]; }
    s = a; s2 = b;
}

// LayerNorm over rows; emits bf16 only (consumed solely by next GEMM's A)
template<int F, int NT>
__global__ __launch_bounds__(NT)
void ln_rows_bf(const float* __restrict__ in, const float* __restrict__ g,
                const float* __restrict__ b, short* __restrict__ out)
{
    constexpr int PER = F / NT;
    const int row = blockIdx.x;
    const int tid = threadIdx.x;
    const float* x = in + (size_t)row * F;
    float v[PER];
    float s = 0.f, s2 = 0.f;
    #pragma unroll
    for (int i = 0; i < PER; ++i) {
        v[i] = x[tid + i * NT];
        s += v[i]; s2 += v[i] * v[i];
    }
    block_reduce2<NT>(s, s2);
    const float mean = s / F;
    const float var  = s2 / F - mean * mean;
    const float rs   = rsqrtf(var + 1e-5f);
    #pragma unroll
    for (int i = 0; i < PER; ++i) {
        int c = tid + i * NT;
        out[(size_t)row * F + c] = f2bf((v[i] - mean) * rs * g[c] + b[c]);
    }
}

// out = LN(relu(u_i*t + v_i*zw_i + cb)) * g + b + resid ; optional bf16 copy
template<int F, int NT, bool WB>
__global__ __launch_bounds__(NT)
void gcn_fuse(const float* __restrict__ zw, const float* __restrict__ t,
              const float* __restrict__ u, const float* __restrict__ vv,
              const float* __restrict__ cb, const float* __restrict__ g,
              const float* __restrict__ b, const float* __restrict__ resid,
              float* __restrict__ out, short* __restrict__ outb)
{
    constexpr int PER = F / NT;
    const int row = blockIdx.x;
    const int tid = threadIdx.x;
    const float ui = u[row], vi = vv[row];
    float y[PER];
    float s = 0.f, s2 = 0.f;
    #pragma unroll
    for (int i = 0; i < PER; ++i) {
        int c = tid + i * NT;
        float val = ui * t[c] + vi * zw[(size_t)row * F + c] + cb[c];
        val = fmaxf(val, 0.f);
        y[i] = val; s += val; s2 += val * val;
    }
    block_reduce2<NT>(s, s2);
    const float mean = s / F;
    const float var  = s2 / F - mean * mean;
    const float rs   = rsqrtf(var + 1e-5f);
    #pragma unroll
    for (int i = 0; i < PER; ++i) {
        int c = tid + i * NT;
        float o = (y[i] - mean) * rs * g[c] + b[c] + resid[(size_t)row * F + c];
        out[(size_t)row * F + c] = o;
        if constexpr (WB) outb[(size_t)row * F + c] = f2bf(o);
    }
}

// s = sigmoid(aw); S = sum(s); u = s*dinv; v = dinv^2*(1-s^2); zero t1..t3
__global__ __launch_bounds__(1024)
void prep(const float* __restrict__ aw, float* __restrict__ s_out,
          float* __restrict__ u, float* __restrict__ v,
          float* __restrict__ t1, float* __restrict__ t2, float* __restrict__ t3)
{
    const int tid = threadIdx.x;
    float acc = 0.f;
    for (int i = tid; i < N_ROWS; i += 1024) {
        float si = 1.f / (1.f + expf(-aw[i]));
        s_out[i] = si;
        acc += si;
    }
    float dummy = 0.f;
    block_reduce2<1024>(acc, dummy);
    const float S = acc;
    for (int i = tid; i < N_ROWS; i += 1024) {
        float si   = s_out[i];
        float dinv = rsqrtf(1.f + si * (S - si));   // deg = 1 + s_i*(S - s_i)
        u[i] = si * dinv;
        v[i] = dinv * dinv * (1.f - si * si);
    }
    if (tid < D_H)   { t1[tid] = 0.f; t2[tid] = 0.f; }
    if (tid < D_OUTF)  t3[tid] = 0.f;
}

// t[c] += sum_r u[r]*zw[r][c]
__global__ void colsum(const float* __restrict__ zw, const float* __restrict__ u,
                       float* __restrict__ t, int F)
{
    const int c  = threadIdx.x;
    const int r0 = blockIdx.x * (N_ROWS / 64);
    float acc = 0.f;
    for (int r = 0; r < N_ROWS / 64; ++r)
        acc += u[r0 + r] * zw[(size_t)(r0 + r) * F + c];
    atomicAdd(&t[c], acc);
}

// mam[i][j] = s_i * s_j  (268 MB streaming write; launched LAST — its region
// doubles as scratch for weights + bf16 activation slots earlier in the launch)
__global__ __launch_bounds__(256)
void mam_kernel(const float* __restrict__ s, float* __restrict__ out)
{
    const float4* s4 = (const float4*)s;
    const size_t total  = (size_t)N_ROWS * (N_ROWS / 4);
    const size_t stride = (size_t)gridDim.x * 256;
    for (size_t g = (size_t)blockIdx.x * 256 + threadIdx.x; g < total; g += stride) {
        int row = (int)(g >> 11);
        int c4  = (int)(g & 2047);
        float  si = s[row];
        float4 sv = s4[c4];
        float4 o;
        o.x = si * sv.x; o.y = si * sv.y; o.z = si * sv.z; o.w = si * sv.w;
        *(float4*)(out + ((size_t)row << 13) + ((size_t)c4 << 2)) = o;
    }
}

// ---------------------------------------------------------------------------
// Orchestration. ws: 3x [8192,512] f32 (48 MiB, round-1-proven) + small vecs.
// Weights + bf16 activation slots live in the mam output region (268 MB),
// which is rewritten by mam_kernel at the very end.
// ---------------------------------------------------------------------------
extern "C" void kernel_launch(void* const* d_in, const int* in_sizes, int n_in,
                              void* d_out, int out_size, void* d_ws, size_t ws_size,
                              hipStream_t stream)
{
    const float* x     = (const float*)d_in[0];
    const float* p1_w  = (const float*)d_in[1];
    const float* p1_b  = (const float*)d_in[2];
    const float* ln0_g = (const float*)d_in[3];
    const float* ln0_b = (const float*)d_in[4];
    const float* p2_w  = (const float*)d_in[5];
    const float* p2_b  = (const float*)d_in[6];
    const float* a1_w  = (const float*)d_in[7];
    const float* a1_b  = (const float*)d_in[8];
    const float* a2_w  = (const float*)d_in[9];
    const float* a2_b  = (const float*)d_in[10];
    const float* a3_w  = (const float*)d_in[11];
    const float* a3_b  = (const float*)d_in[12];
    const float* c1_w  = (const float*)d_in[13];
    const float* c1_b  = (const float*)d_in[14];
    const float* ln1_g = (const float*)d_in[15];
    const float* ln1_b = (const float*)d_in[16];
    const float* c2_w  = (const float*)d_in[17];
    const float* c2_b  = (const float*)d_in[18];
    const float* ln2_g = (const float*)d_in[19];
    const float* ln2_b = (const float*)d_in[20];
    const float* c3_w  = (const float*)d_in[21];
    const float* c3_b  = (const float*)d_in[22];
    const float* ln3_g = (const float*)d_in[23];
    const float* ln3_b = (const float*)d_in[24];
    const float* res_w = (const float*)d_in[25];
    const float* res_b = (const float*)d_in[26];

    float* ws    = (float*)d_ws;
    float* bufA  = ws;                                  // h0 -> x1
    float* bufB  = ws + (size_t)N_ROWS * D_H;           // h  -> x2
    float* bufC  = ws + (size_t)2 * N_ROWS * D_H;       // g1 -> zw1 -> zw2 -> zw3+resb
    float* sm0   = ws + (size_t)3 * N_ROWS * D_H;
    float* s_buf = sm0;
    float* u_buf = sm0 + N_ROWS;
    float* v_buf = sm0 + 2 * N_ROWS;
    float* t1    = sm0 + 3 * N_ROWS;
    float* t2    = t1 + D_H;
    float* t3    = t2 + D_H;
    float* zw3   = bufC;
    float* resb  = bufC + (size_t)N_ROWS * D_OUTF;

    float* out_x3  = (float*)d_out;
    float* out_aw  = out_x3 + (size_t)N_ROWS * D_OUTF;
    float* out_mam = out_aw + N_ROWS;
    short* Z     = (short*)out_mam;                     // scratch in mam region
    short* slot1 = Z + OFF_SLOT1;                       // h_ln -> x1b
    short* slot2 = Z + OFF_SLOT2;                       // hb   -> x2b

    dim3 blk(256);
    dim3 tb(32, 8);
    dim3 g512(4, 128);   // N=512 GEMMs: 512 blocks = 2 blocks/CU
    dim3 g256(2, 128);   // N=256 fused c3+res GEMM

    wtrans<<<dim3(1024, 8), tb, 0, stream>>>(p1_w, p2_w, a1_w, a2_w, c1_w, c2_w, c3_w, res_w, Z);

    // projection
    gemm<true,  EPI_RELU,  D_IN><<<g512, blk, 0, stream>>>(x, Z + OFF_P1T, p1_b, nullptr, nullptr, nullptr, bufA, nullptr, D_H);
    ln_rows_bf<D_H, 256><<<N_ROWS, 256, 0, stream>>>(bufA, ln0_g, ln0_b, slot1);
    gemm<false, EPI_BIAS2, D_H><<<g512, blk, 0, stream>>>(slot1, Z + OFF_P2T, p2_b, nullptr, nullptr, nullptr, bufB, slot2, D_H);
    // attention gate: g1 = sigmoid(h@a1+b); aw = (g1*tanh(h@a2+b))@a3_w + a3_b
    gemm<false, EPI_SIGMOID, D_H><<<g512, blk, 0, stream>>>(slot2, Z + OFF_A1T, a1_b, nullptr, a3_b, out_aw, bufC, nullptr, D_H);
    gemm<false, EPI_TANHMUL, D_H><<<g512, blk, 0, stream>>>(slot2, Z + OFF_A2T, a2_b, bufC, a3_w, out_aw, nullptr, nullptr, D_H);
    prep<<<1, 1024, 0, stream>>>(out_aw, s_buf, u_buf, v_buf, t1, t2, t3);
    // GCN layer 1
    gemm<false, EPI_NONE,  D_H><<<g512, blk, 0, stream>>>(slot2, Z + OFF_C1T, nullptr, nullptr, nullptr, nullptr, bufC, nullptr, D_H);
    colsum<<<64, D_H, 0, stream>>>(bufC, u_buf, t1, D_H);
    gcn_fuse<D_H, 256, true><<<N_ROWS, 256, 0, stream>>>(bufC, t1, u_buf, v_buf, c1_b, ln1_g, ln1_b, bufB, bufA, slot1);
    // GCN layer 2
    gemm<false, EPI_NONE,  D_H><<<g512, blk, 0, stream>>>(slot1, Z + OFF_C2T, nullptr, nullptr, nullptr, nullptr, bufC, nullptr, D_H);
    colsum<<<64, D_H, 0, stream>>>(bufC, u_buf, t2, D_H);
    gcn_fuse<D_H, 256, true><<<N_ROWS, 256, 0, stream>>>(bufC, t2, u_buf, v_buf, c2_b, ln2_g, ln2_b, bufA, bufB, slot2);
    // GCN layer 3 + residual projection (fused N=256 GEMM)
    gemm<false, EPI_C3RES, D_H><<<g256, blk, 0, stream>>>(slot2, Z + OFF_C3T, res_b, nullptr, nullptr, resb, zw3, nullptr, 256);
    colsum<<<64, D_OUTF, 0, stream>>>(zw3, u_buf, t3, D_OUTF);
    gcn_fuse<D_OUTF, 128, false><<<N_ROWS, 128, 0, stream>>>(zw3, t3, u_buf, v_buf, c3_b, ln3_g, ln3_b, resb, out_x3, nullptr);
    // mam LAST: overwrites the scratch region
    mam_kernel<<<2048, 256, 0, stream>>>(s_buf, out_mam);
}

// Round 3
// 220.412 us; speedup vs baseline: 3.1845x; 1.1807x over previous
//
#include <hip/hip_runtime.h>
#include <hip/hip_bf16.h>
#include <math.h>

// Problem dims (fixed by reference)
#define N_ROWS 8192
#define D_IN   2048
#define D_H    512
#define D_OUTF 128

typedef __attribute__((ext_vector_type(8))) short bf16x8;
typedef __attribute__((ext_vector_type(4))) float f32x4;

enum { EPI_RELU = 0, EPI_BIAS2 = 1, EPI_A12 = 2, EPI_ZW = 3, EPI_C3RES = 4 };

__device__ __forceinline__ short f2bf(float f) {
    unsigned u = __builtin_bit_cast(unsigned, f);
    u += 0x7fffu + ((u >> 16) & 1u);          // RNE to bf16
    return (short)(u >> 16);
}

// Weight scratch layout (element offsets into the mam-region scratch, shorts)
constexpr size_t OFF_P1T  = 0;          // [512][2048]
constexpr size_t OFF_P2T  = 1048576;    // [512][512]
constexpr size_t OFF_A1T  = 1310720;
constexpr size_t OFF_A2T  = 1572864;
constexpr size_t OFF_C1T  = 1835008;
constexpr size_t OFF_C2T  = 2097152;
constexpr size_t OFF_C3T  = 2359296;    // [128][512]
constexpr size_t OFF_REST = 2424832;    // [128][512]
constexpr size_t OFF_SLOT1 = 4194304;   // bf16 [8192][512] activation slot
constexpr size_t OFF_SLOT2 = 8388608;   // bf16 [8192][512] activation slot

// ---------------------------------------------------------------------------
// Batched weight transpose+convert: W[K][N] f32 -> Wt[N][K] bf16, 32x32 tiles.
// blockIdx.y == 8 lane zeroes out_aw (must precede a12's atomics).
// ---------------------------------------------------------------------------
__global__ __launch_bounds__(256)
void wtrans(const float* __restrict__ p1, const float* __restrict__ p2,
            const float* __restrict__ a1, const float* __restrict__ a2,
            const float* __restrict__ c1, const float* __restrict__ c2,
            const float* __restrict__ c3, const float* __restrict__ rs,
            short* __restrict__ z, float* __restrict__ aw0)
{
    __shared__ float t[32][33];
    const int w = blockIdx.y;
    const int tile = blockIdx.x;
    if (w == 8) {                       // zero aw accumulator
        int i = tile * 256 + threadIdx.y * 32 + threadIdx.x;
        if (i < N_ROWS) aw0[i] = 0.f;
        return;
    }
    const float* src; short* dst; int Kw, Nw;
    switch (w) {
        case 0: src = p1; dst = z + OFF_P1T;  Kw = 2048; Nw = 512; break;
        case 1: src = p2; dst = z + OFF_P2T;  Kw = 512;  Nw = 512; break;
        case 2: src = a1; dst = z + OFF_A1T;  Kw = 512;  Nw = 512; break;
        case 3: src = a2; dst = z + OFF_A2T;  Kw = 512;  Nw = 512; break;
        case 4: src = c1; dst = z + OFF_C1T;  Kw = 512;  Nw = 512; break;
        case 5: src = c2; dst = z + OFF_C2T;  Kw = 512;  Nw = 512; break;
        case 6: src = c3; dst = z + OFF_C3T;  Kw = 512;  Nw = 128; break;
        default: src = rs; dst = z + OFF_REST; Kw = 512; Nw = 128; break;
    }
    const int txc = Nw >> 5, tyc = Kw >> 5;
    if (tile >= txc * tyc) return;
    const int tc = tile % txc, tr = tile / txc;
    const int x = threadIdx.x, y = threadIdx.y;
    #pragma unroll
    for (int j = 0; j < 4; ++j)
        t[y + 8 * j][x] = src[(size_t)(tr * 32 + y + 8 * j) * Nw + tc * 32 + x];
    __syncthreads();
    #pragma unroll
    for (int j = 0; j < 4; ++j)
        dst[(size_t)(tc * 32 + y + 8 * j) * Kw + tr * 32 + x] = f2bf(t[x][y + 8 * j]);
}

// ---------------------------------------------------------------------------
// bf16 MFMA GEMM: BM=64, BN=128, BK=64, 256 thr = 4 waves (2x2), wave tile
// 32x64. A: [M][K] f32 or bf16 k-major; B (and optional B2): [N][K] bf16
// k-major. LDS double-buffered, XOR-swizzled (c16 ^= row&7) write+read ->
// conflict-free b128 reads, ONE barrier per K-step. Global loads for step
// s+2 issued under step s's MFMAs.
// ---------------------------------------------------------------------------
template<bool AF32, bool DUALB, int EPI, int KT>
__global__ __launch_bounds__(256)
void gemm(const void* __restrict__ Ap, const short* __restrict__ Bt,
          const short* __restrict__ Bt2,
          const float* __restrict__ bias, const float* __restrict__ bias2,
          const float* __restrict__ sb,
          const float* __restrict__ auxw, float* __restrict__ auxo,
          float* __restrict__ C, float* __restrict__ C2,
          short* __restrict__ Cb, int N)
{
    constexpr int NSTEP = KT / 64;
    constexpr int BROWS = DUALB ? 256 : 128;
    __shared__ short lds_a[2][64 * 64];
    __shared__ short lds_b[2][BROWS * 64];
    const int tid = threadIdx.x;
    // XCD-aware swizzle (nwg % 8 == 0 for all grids here)
    const int gx   = gridDim.x;
    const int orig = blockIdx.y * gx + blockIdx.x;
    const int cpx  = (gx * gridDim.y) >> 3;
    const int wg   = (orig & 7) * cpx + (orig >> 3);
    const int bx   = wg % gx;
    const int by   = wg / gx;
    const int row0 = by * 64;
    const int col0 = bx * 128;
    const int lane = tid & 63;
    const int wid  = tid >> 6;
    const int wm   = (wid >> 1) * 32;
    const int wn   = (wid & 1) * 64;
    const int l15  = lane & 15;
    const int lhi  = lane >> 4;

    f32x4 acc[2][4], acc2[2][4];
    #pragma unroll
    for (int i = 0; i < 2; ++i)
        #pragma unroll
        for (int j = 0; j < 4; ++j) {
            f32x4 z = {0.f, 0.f, 0.f, 0.f};
            acc[i][j] = z;
            if constexpr (DUALB) acc2[i][j] = z;
        }

    bf16x8 ra[2], rb[4], rb2[4];

    auto load_a = [&](int kt) {
        #pragma unroll
        for (int i = 0; i < 2; ++i) {
            const int q = tid + (i << 8);      // 0..511
            const int r = q >> 3, c16 = q & 7;
            if constexpr (AF32) {
                const float* p = (const float*)Ap + (size_t)(row0 + r) * KT + kt + c16 * 8;
                float4 u0 = *(const float4*)p;
                float4 u1 = *(const float4*)(p + 4);
                bf16x8 v;
                v[0] = f2bf(u0.x); v[1] = f2bf(u0.y); v[2] = f2bf(u0.z); v[3] = f2bf(u0.w);
                v[4] = f2bf(u1.x); v[5] = f2bf(u1.y); v[6] = f2bf(u1.z); v[7] = f2bf(u1.w);
                ra[i] = v;
            } else {
                ra[i] = *(const bf16x8*)((const short*)Ap + (size_t)(row0 + r) * KT + kt + c16 * 8);
            }
        }
    };
    auto load_b = [&](int kt) {
        #pragma unroll
        for (int i = 0; i < 4; ++i) {
            const int q = tid + (i << 8);      // 0..1023
            const int r = q >> 3, c16 = q & 7;
            rb[i] = *(const bf16x8*)(Bt + (size_t)(col0 + r) * KT + kt + c16 * 8);
            if constexpr (DUALB)
                rb2[i] = *(const bf16x8*)(Bt2 + (size_t)(col0 + r) * KT + kt + c16 * 8);
        }
    };
    auto write_tile = [&](int p) {
        #pragma unroll
        for (int i = 0; i < 2; ++i) {
            const int q = tid + (i << 8);
            const int r = q >> 3, c16 = q & 7;
            *(bf16x8*)(lds_a[p] + r * 64 + ((c16 ^ (r & 7)) << 3)) = ra[i];
        }
        #pragma unroll
        for (int i = 0; i < 4; ++i) {
            const int q = tid + (i << 8);
            const int r = q >> 3, c16 = q & 7;
            *(bf16x8*)(lds_b[p] + r * 64 + ((c16 ^ (r & 7)) << 3)) = rb[i];
            if constexpr (DUALB)
                *(bf16x8*)(lds_b[p] + (r + 128) * 64 + ((c16 ^ (r & 7)) << 3)) = rb2[i];
        }
    };

    load_a(0); load_b(0);
    write_tile(0);
    if (NSTEP > 1) { load_a(64); load_b(64); }

    #pragma unroll 2
    for (int s = 0; s < NSTEP; ++s) {
        __syncthreads();                       // buf[s&1] ready; prior compute done
        const int p = s & 1;
        const short* la = lds_a[p];
        const short* lb = lds_b[p];
        #pragma unroll
        for (int kk = 0; kk < 2; ++kk) {
            bf16x8 af[2], bfr[4], bfr2[4];
            #pragma unroll
            for (int mi = 0; mi < 2; ++mi) {
                const int row = wm + mi * 16 + l15;
                af[mi] = *(const bf16x8*)(la + row * 64 + (((kk * 4 + lhi) ^ (row & 7)) << 3));
            }
            #pragma unroll
            for (int ni = 0; ni < 4; ++ni) {
                const int row = wn + ni * 16 + l15;
                bfr[ni] = *(const bf16x8*)(lb + row * 64 + (((kk * 4 + lhi) ^ (row & 7)) << 3));
                if constexpr (DUALB)
                    bfr2[ni] = *(const bf16x8*)(lb + (row + 128) * 64 + (((kk * 4 + lhi) ^ (row & 7)) << 3));
            }
            #pragma unroll
            for (int mi = 0; mi < 2; ++mi)
                #pragma unroll
                for (int ni = 0; ni < 4; ++ni) {
                    acc[mi][ni] = __builtin_amdgcn_mfma_f32_16x16x32_bf16(
                        af[mi], bfr[ni], acc[mi][ni], 0, 0, 0);
                    if constexpr (DUALB)
                        acc2[mi][ni] = __builtin_amdgcn_mfma_f32_16x16x32_bf16(
                            af[mi], bfr2[ni], acc2[mi][ni], 0, 0, 0);
                }
        }
        if (s + 1 < NSTEP) {
            write_tile((s + 1) & 1);           // vmcnt wait for s+1 loads lands here
            if (s + 2 < NSTEP) { load_a((s + 2) * 64); load_b((s + 2) * 64); }
        }
    }

    // epilogues: C/D row=(lane>>4)*4+j, col=lane&15 [verified rounds 1-2]
    if constexpr (EPI == EPI_A12) {
        // gate = sigmoid(acc+b1)*tanh(acc2+b2); row-dot with a3_w -> atomicAdd aw
        float pd[2][4];
        #pragma unroll
        for (int mi = 0; mi < 2; ++mi)
            #pragma unroll
            for (int j = 0; j < 4; ++j) pd[mi][j] = 0.f;
        #pragma unroll
        for (int mi = 0; mi < 2; ++mi)
            #pragma unroll
            for (int ni = 0; ni < 4; ++ni) {
                const int col = col0 + wn + ni * 16 + l15;
                const float b1 = bias[col], b2 = bias2[col], w3 = auxw[col];
                #pragma unroll
                for (int j = 0; j < 4; ++j) {
                    float g1 = 1.f / (1.f + expf(-(acc[mi][ni][j] + b1)));
                    float g2 = tanhf(acc2[mi][ni][j] + b2);
                    pd[mi][j] += g1 * g2 * w3;
                }
            }
        #pragma unroll
        for (int mi = 0; mi < 2; ++mi)
            #pragma unroll
            for (int j = 0; j < 4; ++j) {
                float v = pd[mi][j];
                v += __shfl_xor(v, 1); v += __shfl_xor(v, 2);
                v += __shfl_xor(v, 4); v += __shfl_xor(v, 8);
                if (l15 == 0) {
                    if (bx == 0 && wn == 0) v += sb[0];   // fold a3_b exactly once/row
                    atomicAdd(&auxo[row0 + wm + mi * 16 + lhi * 4 + j], v);
                }
            }
    } else if constexpr (EPI == EPI_ZW) {
        // C = acc; t[col] += sum_rows u[row]*val  (colsum fused)
        float ur[2][4];
        #pragma unroll
        for (int mi = 0; mi < 2; ++mi)
            #pragma unroll
            for (int j = 0; j < 4; ++j)
                ur[mi][j] = auxw[row0 + wm + mi * 16 + lhi * 4 + j];
        float tp[4] = {0.f, 0.f, 0.f, 0.f};
        #pragma unroll
        for (int mi = 0; mi < 2; ++mi)
            #pragma unroll
            for (int ni = 0; ni < 4; ++ni) {
                const int col = col0 + wn + ni * 16 + l15;
                #pragma unroll
                for (int j = 0; j < 4; ++j) {
                    const int row = row0 + wm + mi * 16 + lhi * 4 + j;
                    const float val = acc[mi][ni][j];
                    C[(size_t)row * N + col] = val;
                    tp[ni] += ur[mi][j] * val;
                }
            }
        #pragma unroll
        for (int ni = 0; ni < 4; ++ni) {
            float v = tp[ni];
            v += __shfl_xor(v, 16); v += __shfl_xor(v, 32);
            if (lhi == 0)
                atomicAdd(&auxo[col0 + wn + ni * 16 + l15], v);
        }
    } else if constexpr (EPI == EPI_C3RES) {
        if (bx == 0) {
            // zw3 (stride 128) + t3 colsum
            float ur[2][4];
            #pragma unroll
            for (int mi = 0; mi < 2; ++mi)
                #pragma unroll
                for (int j = 0; j < 4; ++j)
                    ur[mi][j] = auxw[row0 + wm + mi * 16 + lhi * 4 + j];
            float tp[4] = {0.f, 0.f, 0.f, 0.f};
            #pragma unroll
            for (int mi = 0; mi < 2; ++mi)
                #pragma unroll
                for (int ni = 0; ni < 4; ++ni) {
                    const int c = wn + ni * 16 + l15;
                    #pragma unroll
                    for (int j = 0; j < 4; ++j) {
                        const int row = row0 + wm + mi * 16 + lhi * 4 + j;
                        const float val = acc[mi][ni][j];
                        C[(size_t)row * D_OUTF + c] = val;
                        tp[ni] += ur[mi][j] * val;
                    }
                }
            #pragma unroll
            for (int ni = 0; ni < 4; ++ni) {
                float v = tp[ni];
                v += __shfl_xor(v, 16); v += __shfl_xor(v, 32);
                if (lhi == 0)
                    atomicAdd(&auxo[wn + ni * 16 + l15], v);
            }
        } else {
            // resb = acc + res_b
            #pragma unroll
            for (int mi = 0; mi < 2; ++mi)
                #pragma unroll
                for (int ni = 0; ni < 4; ++ni) {
                    const int c = wn + ni * 16 + l15;
                    #pragma unroll
                    for (int j = 0; j < 4; ++j) {
                        const int row = row0 + wm + mi * 16 + lhi * 4 + j;
                        C2[(size_t)row * D_OUTF + c] = acc[mi][ni][j] + bias[c];
                    }
                }
        }
    } else {
        #pragma unroll
        for (int mi = 0; mi < 2; ++mi)
            #pragma unroll
            for (int ni = 0; ni < 4; ++ni) {
                const int col = col0 + wn + ni * 16 + l15;
                #pragma unroll
                for (int j = 0; j < 4; ++j) {
                    const int row = row0 + wm + mi * 16 + lhi * 4 + j;
                    float val = acc[mi][ni][j] + bias[col];
                    if constexpr (EPI == EPI_RELU) {
                        C[(size_t)row * N + col] = fmaxf(val, 0.f);
                    } else { // EPI_BIAS2
                        C[(size_t)row * N + col] = val;
                        Cb[(size_t)row * N + col] = f2bf(val);
                    }
                }
            }
    }
}

// ---------------------------------------------------------------------------
template<int NT>
__device__ __forceinline__ void block_reduce2(float& s, float& s2)
{
    #pragma unroll
    for (int o = 32; o > 0; o >>= 1) {
        s  += __shfl_down(s,  o);
        s2 += __shfl_down(s2, o);
    }
    __shared__ float sm[2][NT / 64];
    const int wid  = threadIdx.x >> 6;
    const int lane = threadIdx.x & 63;
    if (lane == 0) { sm[0][wid] = s; sm[1][wid] = s2; }
    __syncthreads();
    float a = 0.f, b = 0.f;
    #pragma unroll
    for (int w = 0; w < NT / 64; ++w) { a += sm[0][w]; b += sm[1][w]; }
    s = a; s2 = b;
}

// LayerNorm over rows; emits bf16 only
template<int F, int NT>
__global__ __launch_bounds__(NT)
void ln_rows_bf(const float* __restrict__ in, const float* __restrict__ g,
                const float* __restrict__ b, short* __restrict__ out)
{
    constexpr int PER = F / NT;
    const int row = blockIdx.x;
    const int tid = threadIdx.x;
    const float* x = in + (size_t)row * F;
    float v[PER];
    float s = 0.f, s2 = 0.f;
    #pragma unroll
    for (int i = 0; i < PER; ++i) {
        v[i] = x[tid + i * NT];
        s += v[i]; s2 += v[i] * v[i];
    }
    block_reduce2<NT>(s, s2);
    const float mean = s / F;
    const float var  = s2 / F - mean * mean;
    const float rs   = rsqrtf(var + 1e-5f);
    #pragma unroll
    for (int i = 0; i < PER; ++i) {
        int c = tid + i * NT;
        out[(size_t)row * F + c] = f2bf((v[i] - mean) * rs * g[c] + b[c]);
    }
}

// out = LN(relu(u_i*t + v_i*zw_i + cb)) * g + b + resid
template<int F, int NT, bool WOUT, bool WB>
__global__ __launch_bounds__(NT)
void gcn_fuse(const float* __restrict__ zw, const float* __restrict__ t,
              const float* __restrict__ u, const float* __restrict__ vv,
              const float* __restrict__ cb, const float* __restrict__ g,
              const float* __restrict__ b, const float* __restrict__ resid,
              float* __restrict__ out, short* __restrict__ outb)
{
    constexpr int PER = F / NT;
    const int row = blockIdx.x;
    const int tid = threadIdx.x;
    const float ui = u[row], vi = vv[row];
    float y[PER];
    float s = 0.f, s2 = 0.f;
    #pragma unroll
    for (int i = 0; i < PER; ++i) {
        int c = tid + i * NT;
        float val = ui * t[c] + vi * zw[(size_t)row * F + c] + cb[c];
        val = fmaxf(val, 0.f);
        y[i] = val; s += val; s2 += val * val;
    }
    block_reduce2<NT>(s, s2);
    const float mean = s / F;
    const float var  = s2 / F - mean * mean;
    const float rs   = rsqrtf(var + 1e-5f);
    #pragma unroll
    for (int i = 0; i < PER; ++i) {
        int c = tid + i * NT;
        float o = (y[i] - mean) * rs * g[c] + b[c] + resid[(size_t)row * F + c];
        if constexpr (WOUT) out[(size_t)row * F + c] = o;
        if constexpr (WB)   outb[(size_t)row * F + c] = f2bf(o);
    }
}

// s = sigmoid(aw); S = sum(s); u = s*dinv; v = dinv^2*(1-s^2); zero t1..t3
__global__ __launch_bounds__(1024)
void prep(const float* __restrict__ aw, float* __restrict__ s_out,
          float* __restrict__ u, float* __restrict__ v,
          float* __restrict__ t1, float* __restrict__ t2, float* __restrict__ t3)
{
    const int tid = threadIdx.x;
    float acc = 0.f;
    for (int i = tid; i < N_ROWS; i += 1024) {
        float si = 1.f / (1.f + expf(-aw[i]));
        s_out[i] = si;
        acc += si;
    }
    float dummy = 0.f;
    block_reduce2<1024>(acc, dummy);
    const float S = acc;
    for (int i = tid; i < N_ROWS; i += 1024) {
        float si   = s_out[i];
        float dinv = rsqrtf(1.f + si * (S - si));   // deg = 1 + s_i*(S - s_i)
        u[i] = si * dinv;
        v[i] = dinv * dinv * (1.f - si * si);
    }
    if (tid < D_H)   { t1[tid] = 0.f; t2[tid] = 0.f; }
    if (tid < D_OUTF)  t3[tid] = 0.f;
}

// mam[i][j] = s_i * s_j  (268 MB streaming write; launched LAST — its region
// doubles as scratch for weights + bf16 activation slots earlier)
__global__ __launch_bounds__(256)
void mam_kernel(const float* __restrict__ s, float* __restrict__ out)
{
    const float4* s4 = (const float4*)s;
    const size_t total  = (size_t)N_ROWS * (N_ROWS / 4);
    const size_t stride = (size_t)gridDim.x * 256;
    for (size_t g = (size_t)blockIdx.x * 256 + threadIdx.x; g < total; g += stride) {
        int row = (int)(g >> 11);
        int c4  = (int)(g & 2047);
        float  si = s[row];
        float4 sv = s4[c4];
        float4 o;
        o.x = si * sv.x; o.y = si * sv.y; o.z = si * sv.z; o.w = si * sv.w;
        *(float4*)(out + ((size_t)row << 13) + ((size_t)c4 << 2)) = o;
    }
}

// ---------------------------------------------------------------------------
extern "C" void kernel_launch(void* const* d_in, const int* in_sizes, int n_in,
                              void* d_out, int out_size, void* d_ws, size_t ws_size,
                              hipStream_t stream)
{
    const float* x     = (const float*)d_in[0];
    const float* p1_w  = (const float*)d_in[1];
    const float* p1_b  = (const float*)d_in[2];
    const float* ln0_g = (const float*)d_in[3];
    const float* ln0_b = (const float*)d_in[4];
    const float* p2_w  = (const float*)d_in[5];
    const float* p2_b  = (const float*)d_in[6];
    const float* a1_w  = (const float*)d_in[7];
    const float* a1_b  = (const float*)d_in[8];
    const float* a2_w  = (const float*)d_in[9];
    const float* a2_b  = (const float*)d_in[10];
    const float* a3_w  = (const float*)d_in[11];
    const float* a3_b  = (const float*)d_in[12];
    const float* c1_w  = (const float*)d_in[13];
    const float* c1_b  = (const float*)d_in[14];
    const float* ln1_g = (const float*)d_in[15];
    const float* ln1_b = (const float*)d_in[16];
    const float* c2_w  = (const float*)d_in[17];
    const float* c2_b  = (const float*)d_in[18];
    const float* ln2_g = (const float*)d_in[19];
    const float* ln2_b = (const float*)d_in[20];
    const float* c3_w  = (const float*)d_in[21];
    const float* c3_b  = (const float*)d_in[22];
    const float* ln3_g = (const float*)d_in[23];
    const float* ln3_b = (const float*)d_in[24];
    const float* res_w = (const float*)d_in[25];
    const float* res_b = (const float*)d_in[26];

    float* ws    = (float*)d_ws;
    float* bufA  = ws;                                  // h0 -> x1
    float* bufB  = ws + (size_t)N_ROWS * D_H;           // h (resid for L1)
    float* bufC  = ws + (size_t)2 * N_ROWS * D_H;       // zw1 -> zw2 -> zw3+resb
    float* sm0   = ws + (size_t)3 * N_ROWS * D_H;
    float* s_buf = sm0;
    float* u_buf = sm0 + N_ROWS;
    float* v_buf = sm0 + 2 * N_ROWS;
    float* t1    = sm0 + 3 * N_ROWS;
    float* t2    = t1 + D_H;
    float* t3    = t2 + D_H;
    float* zw3   = bufC;
    float* resb  = bufC + (size_t)N_ROWS * D_OUTF;

    float* out_x3  = (float*)d_out;
    float* out_aw  = out_x3 + (size_t)N_ROWS * D_OUTF;
    float* out_mam = out_aw + N_ROWS;
    short* Z     = (short*)out_mam;                     // scratch in mam region
    short* slot1 = Z + OFF_SLOT1;                       // h_ln -> x1b
    short* slot2 = Z + OFF_SLOT2;                       // hb   -> x2b

    dim3 blk(256);
    dim3 tb(32, 8);
    dim3 g512(4, 128);   // 512 blocks
    dim3 g256(2, 128);   // 256 blocks

    wtrans<<<dim3(1024, 9), tb, 0, stream>>>(p1_w, p2_w, a1_w, a2_w, c1_w, c2_w, c3_w, res_w, Z, out_aw);

    // projection
    gemm<true,  false, EPI_RELU,  D_IN><<<g512, blk, 0, stream>>>(
        x, Z + OFF_P1T, nullptr, p1_b, nullptr, nullptr, nullptr, nullptr, bufA, nullptr, nullptr, D_H);
    ln_rows_bf<D_H, 256><<<N_ROWS, 256, 0, stream>>>(bufA, ln0_g, ln0_b, slot1);
    gemm<false, false, EPI_BIAS2, D_H><<<g512, blk, 0, stream>>>(
        slot1, Z + OFF_P2T, nullptr, p2_b, nullptr, nullptr, nullptr, nullptr, bufB, nullptr, slot2, D_H);
    // attention gate: aw = (sigmoid(h@a1+b1)*tanh(h@a2+b2))@a3_w + a3_b  (one dual-B GEMM)
    gemm<false, true,  EPI_A12,  D_H><<<g512, blk, 0, stream>>>(
        slot2, Z + OFF_A1T, Z + OFF_A2T, a1_b, a2_b, a3_b, a3_w, out_aw, nullptr, nullptr, nullptr, D_H);
    prep<<<1, 1024, 0, stream>>>(out_aw, s_buf, u_buf, v_buf, t1, t2, t3);
    // GCN layer 1 (colsum fused into GEMM epilogue)
    gemm<false, false, EPI_ZW,   D_H><<<g512, blk, 0, stream>>>(
        slot2, Z + OFF_C1T, nullptr, nullptr, nullptr, nullptr, u_buf, t1, bufC, nullptr, nullptr, D_H);
    gcn_fuse<D_H, 256, true,  true><<<N_ROWS, 256, 0, stream>>>(
        bufC, t1, u_buf, v_buf, c1_b, ln1_g, ln1_b, bufB, bufA, slot1);
    // GCN layer 2
    gemm<false, false, EPI_ZW,   D_H><<<g512, blk, 0, stream>>>(
        slot1, Z + OFF_C2T, nullptr, nullptr, nullptr, nullptr, u_buf, t2, bufC, nullptr, nullptr, D_H);
    gcn_fuse<D_H, 256, false, true><<<N_ROWS, 256, 0, stream>>>(
        bufC, t2, u_buf, v_buf, c2_b, ln2_g, ln2_b, bufA, nullptr, slot2);
    // GCN layer 3 + residual projection (fused N=256 GEMM, colsum fused)
    gemm<false, false, EPI_C3RES, D_H><<<g256, blk, 0, stream>>>(
        slot2, Z + OFF_C3T, nullptr, res_b, nullptr, nullptr, u_buf, t3, zw3, resb, nullptr, 256);
    gcn_fuse<D_OUTF, 128, true, false><<<N_ROWS, 128, 0, stream>>>(
        zw3, t3, u_buf, v_buf, c3_b, ln3_g, ln3_b, resb, out_x3, nullptr);
    // mam LAST: overwrites the scratch region
    mam_kernel<<<2048, 256, 0, stream>>>(s_buf, out_mam);
}

// Round 5
// 190.887 us; speedup vs baseline: 3.6770x; 1.1547x over previous
//
#include <hip/hip_runtime.h>
#include <hip/hip_bf16.h>
#include <math.h>

// Problem dims (fixed by reference)
#define N_ROWS 8192
#define D_IN   2048
#define D_H    512
#define D_OUTF 128

typedef __attribute__((ext_vector_type(8))) short bf16x8;
typedef __attribute__((ext_vector_type(4))) float f32x4;

enum { EPI_H0B = 0, EPI_BIASB = 1, EPI_A12 = 2, EPI_ZW = 3, EPI_C3RES = 4 };

__device__ __forceinline__ short f2bf(float f) {
    unsigned u = __builtin_bit_cast(unsigned, f);
    u += 0x7fffu + ((u >> 16) & 1u);          // RNE to bf16
    return (short)(u >> 16);
}
__device__ __forceinline__ float bf2f(short h) {
    unsigned u = ((unsigned)(unsigned short)h) << 16;
    return __builtin_bit_cast(float, u);
}

// global -> LDS direct (16B/lane). Dest must be wave-uniform base; HW adds lane*16.
#define GLOAD16(gsrc, ldst) \
    __builtin_amdgcn_global_load_lds( \
        (const __attribute__((address_space(1))) void*)(gsrc), \
        (__attribute__((address_space(3))) void*)(ldst), 16, 0, 0)

// Weight scratch layout (element offsets into the mam-region scratch, shorts)
constexpr size_t OFF_P1T  = 0;          // [512][2048]
constexpr size_t OFF_P2T  = 1048576;    // [512][512]
constexpr size_t OFF_A1T  = 1310720;
constexpr size_t OFF_A2T  = 1572864;
constexpr size_t OFF_C1T  = 1835008;
constexpr size_t OFF_C2T  = 2097152;
constexpr size_t OFF_C3T  = 2359296;    // [128][512]
constexpr size_t OFF_REST = 2424832;    // [128][512]
constexpr size_t OFF_SLOT1 = 4194304;   // bf16 [8192][512] activation slot
constexpr size_t OFF_SLOT2 = 8388608;   // bf16 [8192][512] activation slot

// ---------------------------------------------------------------------------
// Batched weight transpose+convert: W[K][N] f32 -> Wt[N][K] bf16, 32x32 tiles.
// blockIdx.y == 8 lane zeroes out_aw (must precede a12's atomics).
// ---------------------------------------------------------------------------
__global__ __launch_bounds__(256)
void wtrans(const float* __restrict__ p1, const float* __restrict__ p2,
            const float* __restrict__ a1, const float* __restrict__ a2,
            const float* __restrict__ c1, const float* __restrict__ c2,
            const float* __restrict__ c3, const float* __restrict__ rs,
            short* __restrict__ z, float* __restrict__ aw0)
{
    __shared__ float t[32][33];
    const int w = blockIdx.y;
    const int tile = blockIdx.x;
    if (w == 8) {                       // zero aw accumulator
        int i = tile * 256 + threadIdx.y * 32 + threadIdx.x;
        if (i < N_ROWS) aw0[i] = 0.f;
        return;
    }
    const float* src; short* dst; int Kw, Nw;
    switch (w) {
        case 0: src = p1; dst = z + OFF_P1T;  Kw = 2048; Nw = 512; break;
        case 1: src = p2; dst = z + OFF_P2T;  Kw = 512;  Nw = 512; break;
        case 2: src = a1; dst = z + OFF_A1T;  Kw = 512;  Nw = 512; break;
        case 3: src = a2; dst = z + OFF_A2T;  Kw = 512;  Nw = 512; break;
        case 4: src = c1; dst = z + OFF_C1T;  Kw = 512;  Nw = 512; break;
        case 5: src = c2; dst = z + OFF_C2T;  Kw = 512;  Nw = 512; break;
        case 6: src = c3; dst = z + OFF_C3T;  Kw = 512;  Nw = 128; break;
        default: src = rs; dst = z + OFF_REST; Kw = 512; Nw = 128; break;
    }
    const int txc = Nw >> 5, tyc = Kw >> 5;
    if (tile >= txc * tyc) return;
    const int tc = tile % txc, tr = tile / txc;
    const int x = threadIdx.x, y = threadIdx.y;
    #pragma unroll
    for (int j = 0; j < 4; ++j)
        t[y + 8 * j][x] = src[(size_t)(tr * 32 + y + 8 * j) * Nw + tc * 32 + x];
    __syncthreads();
    #pragma unroll
    for (int j = 0; j < 4; ++j)
        dst[(size_t)(tc * 32 + y + 8 * j) * Kw + tr * 32 + x] = f2bf(t[x][y + 8 * j]);
}

// ---------------------------------------------------------------------------
// bf16 MFMA GEMM: BM=64, BN=128, BK=64, 256 thr = 4 waves (2x2), wave tile
// 32x64. A: [M][K] f32 (reg-staged) or bf16 (global_load_lds); B/B2: [N][K]
// bf16 k-major. LDS double-buffered; LINEAR dest + inverse-swizzled SOURCE
// column + swizzled ds_read (both-sides rule). gload path: counted vmcnt
// (6 or 10, never 0 mid-loop) + raw s_barrier keeps next tile in flight.
// ---------------------------------------------------------------------------
template<bool AF32, bool DUALB, int EPI, int KT>
__global__ __launch_bounds__(256)
void gemm(const void* __restrict__ Ap, const short* __restrict__ Bt,
          const short* __restrict__ Bt2,
          const float* __restrict__ bias, const float* __restrict__ bias2,
          const float* __restrict__ sb,
          const float* __restrict__ auxw, float* __restrict__ auxo,
          float* __restrict__ C, float* __restrict__ C2,
          short* __restrict__ Cb, int N)
{
    constexpr int NSTEP = KT / 64;
    constexpr int BROWS = DUALB ? 256 : 128;
    __shared__ short lds_a[2][64 * 64];
    __shared__ short lds_b[2][BROWS * 64];
    const int tid = threadIdx.x;
    // XCD-aware swizzle (nwg % 8 == 0 for all grids here)
    const int gx   = gridDim.x;
    const int orig = blockIdx.y * gx + blockIdx.x;
    const int cpx  = (gx * gridDim.y) >> 3;
    const int wg   = (orig & 7) * cpx + (orig >> 3);
    const int bx   = wg % gx;
    const int by   = wg / gx;
    const int row0 = by * 64;
    const int col0 = bx * 128;
    const int lane = tid & 63;
    const int wid  = tid >> 6;
    const int wm   = (wid >> 1) * 32;
    const int wn   = (wid & 1) * 64;
    const int l15  = lane & 15;
    const int lhi  = lane >> 4;

    f32x4 acc[2][4], acc2[2][4];
    #pragma unroll
    for (int i = 0; i < 2; ++i)
        #pragma unroll
        for (int j = 0; j < 4; ++j) {
            f32x4 z = {0.f, 0.f, 0.f, 0.f};
            acc[i][j] = z;
            if constexpr (DUALB) acc2[i][j] = z;
        }

    auto do_compute = [&](int p) {
        const short* la = lds_a[p];
        const short* lb = lds_b[p];
        #pragma unroll
        for (int kk = 0; kk < 2; ++kk) {
            bf16x8 af[2], bfr[4], bfr2[4];
            #pragma unroll
            for (int mi = 0; mi < 2; ++mi) {
                const int row = wm + mi * 16 + l15;
                af[mi] = *(const bf16x8*)(la + row * 64 + (((kk * 4 + lhi) ^ (row & 7)) << 3));
            }
            #pragma unroll
            for (int ni = 0; ni < 4; ++ni) {
                const int row = wn + ni * 16 + l15;
                bfr[ni] = *(const bf16x8*)(lb + row * 64 + (((kk * 4 + lhi) ^ (row & 7)) << 3));
                if constexpr (DUALB)
                    bfr2[ni] = *(const bf16x8*)(lb + (row + 128) * 64 + (((kk * 4 + lhi) ^ (row & 7)) << 3));
            }
            #pragma unroll
            for (int mi = 0; mi < 2; ++mi)
                #pragma unroll
                for (int ni = 0; ni < 4; ++ni) {
                    acc[mi][ni] = __builtin_amdgcn_mfma_f32_16x16x32_bf16(
                        af[mi], bfr[ni], acc[mi][ni], 0, 0, 0);
                    if constexpr (DUALB)
                        acc2[mi][ni] = __builtin_amdgcn_mfma_f32_16x16x32_bf16(
                            af[mi], bfr2[ni], acc2[mi][ni], 0, 0, 0);
                }
        }
    };

    if constexpr (!AF32) {
        // ---- async gload_lds path (A is bf16 k-major) ----
        auto stage = [&](int p, int kt) {
            #pragma unroll
            for (int i = 0; i < 2; ++i) {
                const int q = tid + (i << 8);
                const int r = q >> 3, c16 = q & 7;
                GLOAD16((const short*)Ap + (size_t)(row0 + r) * KT + kt + ((c16 ^ (r & 7)) << 3),
                        lds_a[p] + (i << 11) + (wid << 9));
            }
            #pragma unroll
            for (int i = 0; i < 4; ++i) {
                const int q = tid + (i << 8);
                const int r = q >> 3, c16 = q & 7;
                GLOAD16(Bt + (size_t)(col0 + r) * KT + kt + ((c16 ^ (r & 7)) << 3),
                        lds_b[p] + (i << 11) + (wid << 9));
                if constexpr (DUALB)
                    GLOAD16(Bt2 + (size_t)(col0 + r) * KT + kt + ((c16 ^ (r & 7)) << 3),
                            lds_b[p] + 8192 + (i << 11) + (wid << 9));
            }
        };
        stage(0, 0);
        if (NSTEP > 1) stage(1, 64);
        for (int s = 0; s < NSTEP; ++s) {
            if (s + 1 < NSTEP) {            // tile s done; tile s+1 stays in flight
                if constexpr (DUALB) asm volatile("s_waitcnt vmcnt(10)" ::: "memory");
                else                 asm volatile("s_waitcnt vmcnt(6)"  ::: "memory");
            } else {
                asm volatile("s_waitcnt vmcnt(0)" ::: "memory");
            }
            __builtin_amdgcn_s_barrier();           // all waves' tile-s parts done
            __builtin_amdgcn_sched_barrier(0);
            do_compute(s & 1);
            __builtin_amdgcn_s_barrier();           // all done reading buf[s&1]
            __builtin_amdgcn_sched_barrier(0);
            if (s + 2 < NSTEP) stage(s & 1, (s + 2) * 64);
        }
    } else {
        // ---- reg-staged path (A is f32, converted in flight) ----
        bf16x8 ra[2], rb[4];
        auto load_a = [&](int kt) {
            #pragma unroll
            for (int i = 0; i < 2; ++i) {
                const int q = tid + (i << 8);
                const int r = q >> 3, c16 = q & 7;
                const float* p = (const float*)Ap + (size_t)(row0 + r) * KT + kt + c16 * 8;
                float4 u0 = *(const float4*)p;
                float4 u1 = *(const float4*)(p + 4);
                bf16x8 v;
                v[0] = f2bf(u0.x); v[1] = f2bf(u0.y); v[2] = f2bf(u0.z); v[3] = f2bf(u0.w);
                v[4] = f2bf(u1.x); v[5] = f2bf(u1.y); v[6] = f2bf(u1.z); v[7] = f2bf(u1.w);
                ra[i] = v;
            }
        };
        auto load_b = [&](int kt) {
            #pragma unroll
            for (int i = 0; i < 4; ++i) {
                const int q = tid + (i << 8);
                const int r = q >> 3, c16 = q & 7;
                rb[i] = *(const bf16x8*)(Bt + (size_t)(col0 + r) * KT + kt + c16 * 8);
            }
        };
        auto write_tile = [&](int p) {
            #pragma unroll
            for (int i = 0; i < 2; ++i) {
                const int q = tid + (i << 8);
                const int r = q >> 3, c16 = q & 7;
                *(bf16x8*)(lds_a[p] + r * 64 + ((c16 ^ (r & 7)) << 3)) = ra[i];
            }
            #pragma unroll
            for (int i = 0; i < 4; ++i) {
                const int q = tid + (i << 8);
                const int r = q >> 3, c16 = q & 7;
                *(bf16x8*)(lds_b[p] + r * 64 + ((c16 ^ (r & 7)) << 3)) = rb[i];
            }
        };
        load_a(0); load_b(0);
        write_tile(0);
        if (NSTEP > 1) { load_a(64); load_b(64); }
        #pragma unroll 2
        for (int s = 0; s < NSTEP; ++s) {
            __syncthreads();
            do_compute(s & 1);
            if (s + 1 < NSTEP) {
                write_tile((s + 1) & 1);
                if (s + 2 < NSTEP) { load_a((s + 2) * 64); load_b((s + 2) * 64); }
            }
        }
    }

    // epilogues: C/D row=(lane>>4)*4+j, col=lane&15 [verified rounds 1-3]
    if constexpr (EPI == EPI_A12) {
        float pd[2][4];
        #pragma unroll
        for (int mi = 0; mi < 2; ++mi)
            #pragma unroll
            for (int j = 0; j < 4; ++j) pd[mi][j] = 0.f;
        #pragma unroll
        for (int mi = 0; mi < 2; ++mi)
            #pragma unroll
            for (int ni = 0; ni < 4; ++ni) {
                const int col = col0 + wn + ni * 16 + l15;
                const float b1 = bias[col], b2 = bias2[col], w3 = auxw[col];
                #pragma unroll
                for (int j = 0; j < 4; ++j) {
                    float g1 = 1.f / (1.f + expf(-(acc[mi][ni][j] + b1)));
                    float g2 = tanhf(acc2[mi][ni][j] + b2);
                    pd[mi][j] += g1 * g2 * w3;
                }
            }
        #pragma unroll
        for (int mi = 0; mi < 2; ++mi)
            #pragma unroll
            for (int j = 0; j < 4; ++j) {
                float v = pd[mi][j];
                v += __shfl_xor(v, 1); v += __shfl_xor(v, 2);
                v += __shfl_xor(v, 4); v += __shfl_xor(v, 8);
                if (l15 == 0) {
                    if (bx == 0 && wn == 0) v += sb[0];   // fold a3_b exactly once/row
                    atomicAdd(&auxo[row0 + wm + mi * 16 + lhi * 4 + j], v);
                }
            }
    } else if constexpr (EPI == EPI_ZW) {
        // Cb = bf16(acc); t[col] += sum_rows u[row]*acc  (colsum fused, fp32-exact)
        float ur[2][4];
        #pragma unroll
        for (int mi = 0; mi < 2; ++mi)
            #pragma unroll
            for (int j = 0; j < 4; ++j)
                ur[mi][j] = auxw[row0 + wm + mi * 16 + lhi * 4 + j];
        float tp[4] = {0.f, 0.f, 0.f, 0.f};
        #pragma unroll
        for (int mi = 0; mi < 2; ++mi)
            #pragma unroll
            for (int ni = 0; ni < 4; ++ni) {
                const int col = col0 + wn + ni * 16 + l15;
                #pragma unroll
                for (int j = 0; j < 4; ++j) {
                    const int row = row0 + wm + mi * 16 + lhi * 4 + j;
                    const float val = acc[mi][ni][j];
                    Cb[(size_t)row * N + col] = f2bf(val);
                    tp[ni] += ur[mi][j] * val;
                }
            }
        #pragma unroll
        for (int ni = 0; ni < 4; ++ni) {
            float v = tp[ni];
            v += __shfl_xor(v, 16); v += __shfl_xor(v, 32);
            if (lhi == 0)
                atomicAdd(&auxo[col0 + wn + ni * 16 + l15], v);
        }
    } else if constexpr (EPI == EPI_C3RES) {
        if (bx == 0) {
            float ur[2][4];
            #pragma unroll
            for (int mi = 0; mi < 2; ++mi)
                #pragma unroll
                for (int j = 0; j < 4; ++j)
                    ur[mi][j] = auxw[row0 + wm + mi * 16 + lhi * 4 + j];
            float tp[4] = {0.f, 0.f, 0.f, 0.f};
            #pragma unroll
            for (int mi = 0; mi < 2; ++mi)
                #pragma unroll
                for (int ni = 0; ni < 4; ++ni) {
                    const int c = wn + ni * 16 + l15;
                    #pragma unroll
                    for (int j = 0; j < 4; ++j) {
                        const int row = row0 + wm + mi * 16 + lhi * 4 + j;
                        const float val = acc[mi][ni][j];
                        C[(size_t)row * D_OUTF + c] = val;
                        tp[ni] += ur[mi][j] * val;
                    }
                }
            #pragma unroll
            for (int ni = 0; ni < 4; ++ni) {
                float v = tp[ni];
                v += __shfl_xor(v, 16); v += __shfl_xor(v, 32);
                if (lhi == 0)
                    atomicAdd(&auxo[wn + ni * 16 + l15], v);
            }
        } else {
            #pragma unroll
            for (int mi = 0; mi < 2; ++mi)
                #pragma unroll
                for (int ni = 0; ni < 4; ++ni) {
                    const int c = wn + ni * 16 + l15;
                    #pragma unroll
                    for (int j = 0; j < 4; ++j) {
                        const int row = row0 + wm + mi * 16 + lhi * 4 + j;
                        C2[(size_t)row * D_OUTF + c] = acc[mi][ni][j] + bias[c];
                    }
                }
        }
    } else {
        #pragma unroll
        for (int mi = 0; mi < 2; ++mi)
            #pragma unroll
            for (int ni = 0; ni < 4; ++ni) {
                const int col = col0 + wn + ni * 16 + l15;
                #pragma unroll
                for (int j = 0; j < 4; ++j) {
                    const int row = row0 + wm + mi * 16 + lhi * 4 + j;
                    float val = acc[mi][ni][j] + bias[col];
                    if constexpr (EPI == EPI_H0B) val = fmaxf(val, 0.f);
                    Cb[(size_t)row * N + col] = f2bf(val);
                }
            }
    }
}

// ---------------------------------------------------------------------------
template<int NT>
__device__ __forceinline__ void block_reduce2(float& s, float& s2)
{
    #pragma unroll
    for (int o = 32; o > 0; o >>= 1) {
        s  += __shfl_down(s,  o);
        s2 += __shfl_down(s2, o);
    }
    __shared__ float sm[2][NT / 64];
    const int wid  = threadIdx.x >> 6;
    const int lane = threadIdx.x & 63;
    if (lane == 0) { sm[0][wid] = s; sm[1][wid] = s2; }
    __syncthreads();
    float a = 0.f, b = 0.f;
    #pragma unroll
    for (int w = 0; w < NT / 64; ++w) { a += sm[0][w]; b += sm[1][w]; }
    s = a; s2 = b;
}

// LayerNorm, wave-per-row (4 rows/block, shfl-only): bf16 in -> bf16 out
__global__ __launch_bounds__(256)
void ln_b(const short* __restrict__ in, const float* __restrict__ g,
          const float* __restrict__ b, short* __restrict__ out)
{
    const int row  = blockIdx.x * 4 + (threadIdx.x >> 6);
    const int lane = threadIdx.x & 63;
    const int c0   = lane * 8;
    bf16x8 h8 = *(const bf16x8*)(in + (size_t)row * D_H + c0);
    float v[8], s = 0.f, s2 = 0.f;
    #pragma unroll
    for (int i = 0; i < 8; ++i) { v[i] = bf2f(h8[i]); s += v[i]; s2 += v[i] * v[i]; }
    #pragma unroll
    for (int o = 1; o < 64; o <<= 1) { s += __shfl_xor(s, o); s2 += __shfl_xor(s2, o); }
    const float mean = s * (1.f / D_H);
    const float rs   = rsqrtf(s2 * (1.f / D_H) - mean * mean + 1e-5f);
    float ga[8], ba[8];
    *(float4*)ga       = *(const float4*)(g + c0);
    *(float4*)(ga + 4) = *(const float4*)(g + c0 + 4);
    *(float4*)ba       = *(const float4*)(b + c0);
    *(float4*)(ba + 4) = *(const float4*)(b + c0 + 4);
    bf16x8 o8;
    #pragma unroll
    for (int i = 0; i < 8; ++i) o8[i] = f2bf((v[i] - mean) * rs * ga[i] + ba[i]);
    *(bf16x8*)(out + (size_t)row * D_H + c0) = o8;
}

// x_next = LN(relu(u_i*t + v_i*zw_i + cb))*g + b + resid ; wave-per-row, bf16
__global__ __launch_bounds__(256)
void fuse_b(const short* __restrict__ zw, const float* __restrict__ t,
            const float* __restrict__ u, const float* __restrict__ vv,
            const float* __restrict__ cb, const float* __restrict__ g,
            const float* __restrict__ b, const short* __restrict__ resid,
            short* __restrict__ out)
{
    const int row  = blockIdx.x * 4 + (threadIdx.x >> 6);
    const int lane = threadIdx.x & 63;
    const int c0   = lane * 8;
    const float ui = u[row], vi = vv[row];
    bf16x8 z8 = *(const bf16x8*)(zw + (size_t)row * D_H + c0);
    float ta[8], ca[8];
    *(float4*)ta       = *(const float4*)(t + c0);
    *(float4*)(ta + 4) = *(const float4*)(t + c0 + 4);
    *(float4*)ca       = *(const float4*)(cb + c0);
    *(float4*)(ca + 4) = *(const float4*)(cb + c0 + 4);
    float y[8], s = 0.f, s2 = 0.f;
    #pragma unroll
    for (int i = 0; i < 8; ++i) {
        float val = fmaxf(ui * ta[i] + vi * bf2f(z8[i]) + ca[i], 0.f);
        y[i] = val; s += val; s2 += val * val;
    }
    #pragma unroll
    for (int o = 1; o < 64; o <<= 1) { s += __shfl_xor(s, o); s2 += __shfl_xor(s2, o); }
    const float mean = s * (1.f / D_H);
    const float rs   = rsqrtf(s2 * (1.f / D_H) - mean * mean + 1e-5f);
    bf16x8 r8 = *(const bf16x8*)(resid + (size_t)row * D_H + c0);
    float ga[8], ba[8];
    *(float4*)ga       = *(const float4*)(g + c0);
    *(float4*)(ga + 4) = *(const float4*)(g + c0 + 4);
    *(float4*)ba       = *(const float4*)(b + c0);
    *(float4*)(ba + 4) = *(const float4*)(b + c0 + 4);
    bf16x8 o8;
    #pragma unroll
    for (int i = 0; i < 8; ++i)
        o8[i] = f2bf((y[i] - mean) * rs * ga[i] + ba[i] + bf2f(r8[i]));
    *(bf16x8*)(out + (size_t)row * D_H + c0) = o8;
}

// layer-3 fuse (F=128, fp32 zw/resid/out), wave-per-row
__global__ __launch_bounds__(256)
void fuse3_f(const float* __restrict__ zw, const float* __restrict__ t,
             const float* __restrict__ u, const float* __restrict__ vv,
             const float* __restrict__ cb, const float* __restrict__ g,
             const float* __restrict__ b, const float* __restrict__ resid,
             float* __restrict__ out)
{
    const int row  = blockIdx.x * 4 + (threadIdx.x >> 6);
    const int lane = threadIdx.x & 63;
    const int c0   = lane * 2;
    const float ui = u[row], vi = vv[row];
    float2 z2 = *(const float2*)(zw + (size_t)row * D_OUTF + c0);
    float y0 = fmaxf(ui * t[c0]     + vi * z2.x + cb[c0],     0.f);
    float y1 = fmaxf(ui * t[c0 + 1] + vi * z2.y + cb[c0 + 1], 0.f);
    float s = y0 + y1, s2 = y0 * y0 + y1 * y1;
    #pragma unroll
    for (int o = 1; o < 64; o <<= 1) { s += __shfl_xor(s, o); s2 += __shfl_xor(s2, o); }
    const float mean = s * (1.f / D_OUTF);
    const float rs   = rsqrtf(s2 * (1.f / D_OUTF) - mean * mean + 1e-5f);
    float2 r2 = *(const float2*)(resid + (size_t)row * D_OUTF + c0);
    float2 o2;
    o2.x = (y0 - mean) * rs * g[c0]     + b[c0]     + r2.x;
    o2.y = (y1 - mean) * rs * g[c0 + 1] + b[c0 + 1] + r2.y;
    *(float2*)(out + (size_t)row * D_OUTF + c0) = o2;
}

// s = sigmoid(aw); S = sum(s); u = s*dinv; v = dinv^2*(1-s^2); zero t1..t3
__global__ __launch_bounds__(1024)
void prep(const float* __restrict__ aw, float* __restrict__ s_out,
          float* __restrict__ u, float* __restrict__ v,
          float* __restrict__ t1, float* __restrict__ t2, float* __restrict__ t3)
{
    const int tid = threadIdx.x;
    float acc = 0.f;
    for (int i = tid; i < N_ROWS; i += 1024) {
        float si = 1.f / (1.f + expf(-aw[i]));
        s_out[i] = si;
        acc += si;
    }
    float dummy = 0.f;
    block_reduce2<1024>(acc, dummy);
    const float S = acc;
    for (int i = tid; i < N_ROWS; i += 1024) {
        float si   = s_out[i];
        float dinv = rsqrtf(1.f + si * (S - si));   // deg = 1 + s_i*(S - s_i)
        u[i] = si * dinv;
        v[i] = dinv * dinv * (1.f - si * si);
    }
    if (tid < D_H)   { t1[tid] = 0.f; t2[tid] = 0.f; }
    if (tid < D_OUTF)  t3[tid] = 0.f;
}

// mam[i][j] = s_i * s_j  (268 MB streaming write; launched LAST — its region
// doubles as scratch for weights + bf16 activation slots earlier)
__global__ __launch_bounds__(256)
void mam_kernel(const float* __restrict__ s, float* __restrict__ out)
{
    const f32x4* s4 = (const f32x4*)s;
    const size_t total  = (size_t)N_ROWS * (N_ROWS / 4);
    const size_t stride = (size_t)gridDim.x * 256;
    for (size_t g = (size_t)blockIdx.x * 256 + threadIdx.x; g < total; g += stride) {
        int row = (int)(g >> 11);
        int c4  = (int)(g & 2047);
        float si = s[row];
        f32x4 sv = s4[c4];
        f32x4 o = si * sv;
        __builtin_nontemporal_store(o, (f32x4*)(out + ((size_t)row << 13) + ((size_t)c4 << 2)));
    }
}

// ---------------------------------------------------------------------------
// ws layout: h0b bf16 8MB | zwb bf16 8MB | zw3 4MB | resb 4MB | smalls (~100KB)
// Weights + slot1/slot2 live in the mam output region (268 MB), rewritten by
// mam_kernel at the very end.
// ---------------------------------------------------------------------------
extern "C" void kernel_launch(void* const* d_in, const int* in_sizes, int n_in,
                              void* d_out, int out_size, void* d_ws, size_t ws_size,
                              hipStream_t stream)
{
    const float* x     = (const float*)d_in[0];
    const float* p1_w  = (const float*)d_in[1];
    const float* p1_b  = (const float*)d_in[2];
    const float* ln0_g = (const float*)d_in[3];
    const float* ln0_b = (const float*)d_in[4];
    const float* p2_w  = (const float*)d_in[5];
    const float* p2_b  = (const float*)d_in[6];
    const float* a1_w  = (const float*)d_in[7];
    const float* a1_b  = (const float*)d_in[8];
    const float* a2_w  = (const float*)d_in[9];
    const float* a2_b  = (const float*)d_in[10];
    const float* a3_w  = (const float*)d_in[11];
    const float* a3_b  = (const float*)d_in[12];
    const float* c1_w  = (const float*)d_in[13];
    const float* c1_b  = (const float*)d_in[14];
    const float* ln1_g = (const float*)d_in[15];
    const float* ln1_b = (const float*)d_in[16];
    const float* c2_w  = (const float*)d_in[17];
    const float* c2_b  = (const float*)d_in[18];
    const float* ln2_g = (const float*)d_in[19];
    const float* ln2_b = (const float*)d_in[20];
    const float* c3_w  = (const float*)d_in[21];
    const float* c3_b  = (const float*)d_in[22];
    const float* ln3_g = (const float*)d_in[23];
    const float* ln3_b = (const float*)d_in[24];
    const float* res_w = (const float*)d_in[25];
    const float* res_b = (const float*)d_in[26];

    float* ws   = (float*)d_ws;
    short* wsS  = (short*)d_ws;
    short* h0b  = wsS;                                 // bf16 [8192][512]
    short* zwb  = wsS + (size_t)N_ROWS * D_H;          // bf16 [8192][512] (zw1, then zw2)
    float* wsF  = ws + (size_t)N_ROWS * D_H / 2 * 2;   // after the two bf16 slots (16MB)
    float* zw3  = wsF;                                 // [8192][128] f32
    float* resb = zw3 + (size_t)N_ROWS * D_OUTF;       // [8192][128] f32
    float* s_buf = resb + (size_t)N_ROWS * D_OUTF;
    float* u_buf = s_buf + N_ROWS;
    float* v_buf = u_buf + N_ROWS;
    float* t1    = v_buf + N_ROWS;
    float* t2    = t1 + D_H;
    float* t3    = t2 + D_H;

    float* out_x3  = (float*)d_out;
    float* out_aw  = out_x3 + (size_t)N_ROWS * D_OUTF;
    float* out_mam = out_aw + N_ROWS;
    short* Z     = (short*)out_mam;                    // scratch in mam region
    short* slot1 = Z + OFF_SLOT1;                      // h_ln -> x1
    short* slot2 = Z + OFF_SLOT2;                      // h    -> x2

    dim3 blk(256);
    dim3 tb(32, 8);
    dim3 g512(4, 128);   // 512 blocks
    dim3 g256(2, 128);   // 256 blocks

    wtrans<<<dim3(1024, 9), tb, 0, stream>>>(p1_w, p2_w, a1_w, a2_w, c1_w, c2_w, c3_w, res_w, Z, out_aw);

    // projection
    gemm<true,  false, EPI_H0B,   D_IN><<<g512, blk, 0, stream>>>(
        x, Z + OFF_P1T, nullptr, p1_b, nullptr, nullptr, nullptr, nullptr, nullptr, nullptr, h0b, D_H);
    ln_b<<<2048, 256, 0, stream>>>(h0b, ln0_g, ln0_b, slot1);
    gemm<false, false, EPI_BIASB, D_H><<<g512, blk, 0, stream>>>(
        slot1, Z + OFF_P2T, nullptr, p2_b, nullptr, nullptr, nullptr, nullptr, nullptr, nullptr, slot2, D_H);
    // attention gate: aw = (sigmoid(h@a1+b1)*tanh(h@a2+b2))@a3_w + a3_b
    gemm<false, true,  EPI_A12,   D_H><<<g512, blk, 0, stream>>>(
        slot2, Z + OFF_A1T, Z + OFF_A2T, a1_b, a2_b, a3_b, a3_w, out_aw, nullptr, nullptr, nullptr, D_H);
    prep<<<1, 1024, 0, stream>>>(out_aw, s_buf, u_buf, v_buf, t1, t2, t3);
    // GCN layer 1
    gemm<false, false, EPI_ZW,    D_H><<<g512, blk, 0, stream>>>(
        slot2, Z + OFF_C1T, nullptr, nullptr, nullptr, nullptr, u_buf, t1, nullptr, nullptr, zwb, D_H);
    fuse_b<<<2048, 256, 0, stream>>>(zwb, t1, u_buf, v_buf, c1_b, ln1_g, ln1_b, slot2, slot1);
    // GCN layer 2
    gemm<false, false, EPI_ZW,    D_H><<<g512, blk, 0, stream>>>(
        slot1, Z + OFF_C2T, nullptr, nullptr, nullptr, nullptr, u_buf, t2, nullptr, nullptr, zwb, D_H);
    fuse_b<<<2048, 256, 0, stream>>>(zwb, t2, u_buf, v_buf, c2_b, ln2_g, ln2_b, slot1, slot2);
    // GCN layer 3 + residual projection (fused N=256 GEMM, colsum fused)
    gemm<false, false, EPI_C3RES, D_H><<<g256, blk, 0, stream>>>(
        slot2, Z + OFF_C3T, nullptr, res_b, nullptr, nullptr, u_buf, t3, zw3, resb, nullptr, 256);
    fuse3_f<<<2048, 256, 0, stream>>>(zw3, t3, u_buf, v_buf, c3_b, ln3_g, ln3_b, resb, out_x3);
    // mam LAST: overwrites the scratch region
    mam_kernel<<<2048, 256, 0, stream>>>(s_buf, out_mam);
}